// Round 11
// baseline (226.453 us; speedup 1.0000x reference)
//
#include <hip/hip_runtime.h>
#include <hip/hip_bf16.h>

typedef __bf16 bf16;
typedef __attribute__((ext_vector_type(2))) __bf16 bf16x2;
typedef __attribute__((ext_vector_type(4))) __bf16 bf16x4;
typedef __attribute__((ext_vector_type(8))) __bf16 bf16x8;
typedef __attribute__((ext_vector_type(4))) float f32x4;

static_assert(sizeof(bf16x8) == 16, "bf16x8 must be 16B");

#define S_LEN 2048
#define BATCH_N 2
#define DM 1024
#define NHEAD 16
#define HDIM 64
#define LOG2E 1.44269504088896f

// async global->LDS, 16 B per lane. LDS dest: wave-uniform base + lane*16.
__device__ __forceinline__ void async_cp16(const void* g, void* l) {
    __builtin_amdgcn_global_load_lds(
        (const __attribute__((address_space(1))) void*)g,
        (__attribute__((address_space(3))) void*)l, 16, 0, 0);
}

// ---------------------------------------------------------------------------
// Fused f32 -> bf16 convert for all 5 tensors in ONE dispatch.
// ---------------------------------------------------------------------------
__global__ __launch_bounds__(256)
void cvt_all(const float* __restrict__ q,
             const float* __restrict__ w0, const float* __restrict__ w1,
             const float* __restrict__ w2, const float* __restrict__ w3,
             bf16* __restrict__ Xb,
             bf16* __restrict__ W0, bf16* __restrict__ W1,
             bf16* __restrict__ W2, bf16* __restrict__ W3) {
    const int blk = blockIdx.x;
    const float* src;
    bf16* dst;
    size_t base;
    if (blk < 2048) {
        src = q; dst = Xb; base = (size_t)blk * 2048;
    } else {
        const int w = (blk - 2048) >> 9;
        const int r = (blk - 2048) & 511;
        base = (size_t)r * 2048;
        src = (w == 0) ? w0 : (w == 1) ? w1 : (w == 2) ? w2 : w3;
        dst = (w == 0) ? W0 : (w == 1) ? W1 : (w == 2) ? W2 : W3;
    }
    const size_t i = base + (size_t)threadIdx.x * 8;
    const f32x4 a = *(const f32x4*)(src + i);
    const f32x4 b = *(const f32x4*)(src + i + 4);
    bf16x8 r8;
    r8[0] = (bf16)a[0]; r8[1] = (bf16)a[1]; r8[2] = (bf16)a[2]; r8[3] = (bf16)a[3];
    r8[4] = (bf16)b[0]; r8[5] = (bf16)b[1]; r8[6] = (bf16)b[2]; r8[7] = (bf16)b[3];
    *(bf16x8*)(dst + i) = r8;
}

// ---------------------------------------------------------------------------
// 128x128 bf16 MFMA GEMM tile (proj): C = A * W^T. r8 form (2-phase dbuf,
// __syncthreads). Kept for proj where grid 256 blocks = 1/CU fits.
// ---------------------------------------------------------------------------
__device__ __forceinline__ void gemm_tile(const bf16* __restrict__ A,
                                          const bf16* __restrict__ W,
                                          int row0, int col0, int Kdim,
                                          f32x4 acc[4][4]) {
    __shared__ bf16 As[2][128 * 32];
    __shared__ bf16 Bs[2][128 * 32];
    const int tid  = threadIdx.x;
    const int lane = tid & 63;
    const int wv   = tid >> 6;
    const int wr = wv >> 1, wc = wv & 1;
    const int qr = lane & 15, quad = lane >> 4;

    const int srow = wv * 16 + (lane >> 2);
    const int scol = (lane & 3) * 8;
    const bf16* Ap = A + (size_t)(row0 + srow) * Kdim + scol;
    const bf16* Wp = W + (size_t)(col0 + srow) * Kdim + scol;

    const f32x4 fzero = {0.f, 0.f, 0.f, 0.f};
    #pragma unroll
    for (int mi = 0; mi < 4; ++mi)
        #pragma unroll
        for (int ni = 0; ni < 4; ++ni)
            acc[mi][ni] = fzero;

#define GSTAGE(k0_, bi_) do { \
    async_cp16(Ap + (k0_),                       As[bi_] + wv * 512); \
    async_cp16(Ap + (size_t)64 * Kdim + (k0_),   As[bi_] + 64 * 32 + wv * 512); \
    async_cp16(Wp + (k0_),                       Bs[bi_] + wv * 512); \
    async_cp16(Wp + (size_t)64 * Kdim + (k0_),   Bs[bi_] + 64 * 32 + wv * 512); \
} while (0)

    const int nsteps = Kdim >> 5;
    GSTAGE(0, 0);
    __syncthreads();

    int cur = 0;
    for (int s = 0; s < nsteps; ++s) {
        if (s + 1 < nsteps) GSTAGE((s + 1) << 5, cur ^ 1);

        bf16x8 af[4], bfr[4];
        #pragma unroll
        for (int mi = 0; mi < 4; ++mi)
            af[mi] = *(const bf16x8*)(As[cur] + (wr * 64 + mi * 16 + qr) * 32 + quad * 8);
        #pragma unroll
        for (int ni = 0; ni < 4; ++ni)
            bfr[ni] = *(const bf16x8*)(Bs[cur] + (wc * 64 + ni * 16 + qr) * 32 + quad * 8);
        #pragma unroll
        for (int mi = 0; mi < 4; ++mi)
            #pragma unroll
            for (int ni = 0; ni < 4; ++ni)
                acc[mi][ni] = __builtin_amdgcn_mfma_f32_16x16x32_bf16(
                    af[mi], bfr[ni], acc[mi][ni], 0, 0, 0);

        __syncthreads();
        cur ^= 1;
    }
#undef GSTAGE
}

// ---------------------------------------------------------------------------
// QKV projection with 256x128 tile, 4 waves (2M x 2N), per-wave 128x64.
// WHY: r10 counters show qkv LDS-read-throughput-bound (~124 B/cyc/CU demand
// vs 85-112 measured ceiling; MfmaUtil 21%, latency fixes r8/r9 null).
// Per-wave intensity WM*WN/(WM+WN): 64x64 -> 32, 128x64 -> 42.7 (+33%);
// LDS bytes/MFMA 768 -> 562 (-27%); L2 staged traffic -25%.
// Grid (16 rows, 8 cols, 3 mats) rows-fastest (r10 W-panel L2 win kept).
//   Q  [b][h][s][dh]   pre-scaled by 0.125*log2(e)
//   K  [b][h][s][dh]
//   Vt [b][h][dh][s]
// ---------------------------------------------------------------------------
__global__ __launch_bounds__(256)
void qkv_kernel(const bf16* __restrict__ X,
                const bf16* __restrict__ Wq, const float* __restrict__ bq,
                const bf16* __restrict__ Wk, const float* __restrict__ bk,
                const bf16* __restrict__ Wv, const float* __restrict__ bv,
                bf16* __restrict__ Q, bf16* __restrict__ Kt, bf16* __restrict__ Vt) {
    __shared__ bf16 As[2][256 * 32];    // 32 KB
    __shared__ bf16 Bs[2][128 * 32];    // 16 KB
    const int mat  = blockIdx.z;
    const bf16*  W    = (mat == 0) ? Wq : (mat == 1) ? Wk : Wv;
    const float* bias = (mat == 0) ? bq : (mat == 1) ? bk : bv;
    const int row0 = blockIdx.x * 256;      // fastest dim = rows (share W-panel)
    const int col0 = blockIdx.y * 128;

    const int tid  = threadIdx.x;
    const int lane = tid & 63;
    const int wv   = tid >> 6;              // 0..3
    const int wr = wv >> 1, wc = wv & 1;
    const int qr = lane & 15, quad = lane >> 4;

    // staging: A 16 KB = 4 chunks x 4 KB, B 8 KB = 2 chunks. Thread covers
    // 16 B at elem tid*8 per chunk: row-in-chunk = tid>>2, col = (tid&3)*8.
    const int sr = tid >> 2;                // 0..63
    const int sc = (tid & 3) * 8;
    const bf16* Ap = X + (size_t)(row0 + sr) * DM + sc;
    const bf16* Wp = W + (size_t)(col0 + sr) * DM + sc;

    const f32x4 fzero = {0.f, 0.f, 0.f, 0.f};
    f32x4 acc[8][4];
    #pragma unroll
    for (int mi = 0; mi < 8; ++mi)
        #pragma unroll
        for (int ni = 0; ni < 4; ++ni)
            acc[mi][ni] = fzero;

#define QSTAGE(k0_, bi_) do { \
    async_cp16(Ap + (k0_),                        As[bi_] + tid * 8); \
    async_cp16(Ap + (size_t)64  * DM + (k0_),     As[bi_] + 2048 + tid * 8); \
    async_cp16(Ap + (size_t)128 * DM + (k0_),     As[bi_] + 4096 + tid * 8); \
    async_cp16(Ap + (size_t)192 * DM + (k0_),     As[bi_] + 6144 + tid * 8); \
    async_cp16(Wp + (k0_),                        Bs[bi_] + tid * 8); \
    async_cp16(Wp + (size_t)64  * DM + (k0_),     Bs[bi_] + 2048 + tid * 8); \
} while (0)

    QSTAGE(0, 0);
    __syncthreads();

    int cur = 0;
    for (int s = 0; s < 32; ++s) {          // K = 1024, BK = 32
        if (s + 1 < 32) QSTAGE((s + 1) << 5, cur ^ 1);

        bf16x8 af[8], bfr[4];
        #pragma unroll
        for (int mi = 0; mi < 8; ++mi)
            af[mi] = *(const bf16x8*)(As[cur] + (wr * 128 + mi * 16 + qr) * 32 + quad * 8);
        #pragma unroll
        for (int ni = 0; ni < 4; ++ni)
            bfr[ni] = *(const bf16x8*)(Bs[cur] + (wc * 64 + ni * 16 + qr) * 32 + quad * 8);
        #pragma unroll
        for (int mi = 0; mi < 8; ++mi)
            #pragma unroll
            for (int ni = 0; ni < 4; ++ni)
                acc[mi][ni] = __builtin_amdgcn_mfma_f32_16x16x32_bf16(
                    af[mi], bfr[ni], acc[mi][ni], 0, 0, 0);

        __syncthreads();
        cur ^= 1;
    }
#undef QSTAGE

    #pragma unroll
    for (int ni = 0; ni < 4; ++ni) {
        const int n  = col0 + wc * 64 + ni * 16 + qr;
        const float bn = bias[n];
        const int h = n >> 6, dh = n & 63;
        #pragma unroll
        for (int mi = 0; mi < 8; ++mi) {
            const int i0 = row0 + wr * 128 + mi * 16 + quad * 4;  // even
            const float v0 = acc[mi][ni][0] + bn;
            const float v1 = acc[mi][ni][1] + bn;
            const float v2 = acc[mi][ni][2] + bn;
            const float v3 = acc[mi][ni][3] + bn;
            if (mat == 2) {
                const int s0 = i0 >> 1;                           // even too
                bf16x2 e0 = {(bf16)v0, (bf16)v2};                 // b = 0
                bf16x2 e1 = {(bf16)v1, (bf16)v3};                 // b = 1
                *(bf16x2*)(Vt + ((size_t)h * HDIM + dh) * S_LEN + s0) = e0;
                *(bf16x2*)(Vt + ((size_t)(NHEAD + h) * HDIM + dh) * S_LEN + s0) = e1;
            } else {
                #pragma unroll
                for (int r = 0; r < 4; ++r) {
                    const int i = i0 + r;
                    const int s = i >> 1, b = i & 1;
                    const float v = (r == 0) ? v0 : (r == 1) ? v1 : (r == 2) ? v2 : v3;
                    if (mat == 0) {
                        Q[((size_t)(b * NHEAD + h) * S_LEN + s) * HDIM + dh] =
                            (bf16)(v * (0.125f * LOG2E));
                    } else {
                        Kt[((size_t)(b * NHEAD + h) * S_LEN + s) * HDIM + dh] = (bf16)v;
                    }
                }
            }
        }
    }
}

// ---------------------------------------------------------------------------
// Single-stage fused causal attention, split-M waves + LDS-staged K/V.
// (unchanged from r10 — measured 44.4 µs; balanced qb map, XCD-locked bh)
// ---------------------------------------------------------------------------
#define PLD 40        // P row stride (bf16)
#define PT  640       // 16*PLD elems per wave

#define MFMA(a, b, c) __builtin_amdgcn_mfma_f32_16x16x32_bf16(a, b, c, 0, 0, 0)
#define EX(x) __builtin_amdgcn_exp2f(x)

__global__ __launch_bounds__(256)
void attn_part(const bf16* __restrict__ Q, const bf16* __restrict__ K,
               const bf16* __restrict__ Vt, bf16* __restrict__ ctx) {
    // [K dbuf 2x4096][V dbuf 2x4096][P 4x1280] = 21504 B
    __shared__ __align__(16) char smem[21504];
    const int tid  = threadIdx.x;
    const int lane = tid & 63;
    const int wave = tid >> 6;
    const int qr = lane & 15, quad = lane >> 4;
    const int bh = blockIdx.x & 31;     // XCD = (blockIdx.x % 8) = bh % 8
    const int j  = blockIdx.x >> 5;
    const int b = bh >> 4, h = bh & 15;

    const char* Kg = (const char*)(K  + (size_t)bh * S_LEN * HDIM);
    const char* Vg = (const char*)(Vt + (size_t)bh * HDIM * S_LEN);
    const bf16* Qb = Q + (size_t)bh * S_LEN * HDIM;
    char* Ksm = smem;
    char* Vsm = smem + 8192;
    bf16* Pw  = (bf16*)(smem + 16384) + wave * PT;
    const f32x4 fzero = {0.f, 0.f, 0.f, 0.f};

    const int qb     = (j < 16) ? (31 - j) : (j - 16);   // balanced pairing
    const int qb0    = qb * 64;
    const int tdiag  = qb * 2;          // tiles >= tdiag carry the causal mask
    const int ntiles = 2 * qb + 2;

    // staging addresses (thread-constant): LDS dest linear, source inv-swizzled
    const int d16   = tid * 16;
    const int ksrow = d16 >> 7;                               // K tile row 0..31
    const int ksoff = (d16 & 127) ^ ((ksrow & 7) << 4);
    const int vsrow = d16 >> 6;                               // V tile row 0..63
    const int vsoff = (d16 & 63) ^ ((vsrow & 3) << 4);
    const size_t kgbase = (size_t)ksrow * 128 + ksoff;
    const size_t vgbase = (size_t)vsrow * (S_LEN * 2) + vsoff;

#define STAGE(t_, bi_) do { \
    async_cp16(Kg + (size_t)(t_) * 4096 + kgbase, Ksm + (bi_) * 4096 + wave * 1024); \
    async_cp16(Vg + (size_t)(t_) * 64   + vgbase, Vsm + (bi_) * 4096 + wave * 1024); \
} while (0)

    // this wave's 16 q rows
    const int qrow0 = qb0 + wave * 16;
    const bf16x8 qlo = *(const bf16x8*)(Qb + (size_t)(qrow0 + qr) * HDIM + quad * 8);
    const bf16x8 qhi = *(const bf16x8*)(Qb + (size_t)(qrow0 + qr) * HDIM + quad * 8 + 32);

    f32x4 o0 = fzero, o1 = fzero, o2 = fzero, o3 = fzero;
    float l = 0.f;

    STAGE(0, 0);
    __syncthreads();

    const int sK = (qr & 7) << 4;
    const int sV = (qr & 3) << 4;

    for (int t = 0; t < ntiles; ++t) {
        const int cur = t & 1;
        if (t + 1 < ntiles) STAGE(t + 1, cur ^ 1);

        const char* Kc = Ksm + cur * 4096;
        const char* Vc = Vsm + cur * 4096;
        const bf16x8 k0 = *(const bf16x8*)(Kc + qr * 128        + ((quad * 16)      ^ sK));
        const bf16x8 k1 = *(const bf16x8*)(Kc + qr * 128        + ((quad * 16 + 64) ^ sK));
        const bf16x8 k2 = *(const bf16x8*)(Kc + (16 + qr) * 128 + ((quad * 16)      ^ sK));
        const bf16x8 k3 = *(const bf16x8*)(Kc + (16 + qr) * 128 + ((quad * 16 + 64) ^ sK));
        const bf16x8 v0 = *(const bf16x8*)(Vc + qr * 64         + ((quad * 16) ^ sV));
        const bf16x8 v1 = *(const bf16x8*)(Vc + (16 + qr) * 64  + ((quad * 16) ^ sV));
        const bf16x8 v2 = *(const bf16x8*)(Vc + (32 + qr) * 64  + ((quad * 16) ^ sV));
        const bf16x8 v3 = *(const bf16x8*)(Vc + (48 + qr) * 64  + ((quad * 16) ^ sV));

        f32x4 sA = MFMA(k0, qlo, fzero); sA = MFMA(k1, qhi, sA);
        f32x4 sB = MFMA(k2, qlo, fzero); sB = MFMA(k3, qhi, sB);

        if (t < tdiag) {
            const float e0 = EX(sA[0]), e1 = EX(sA[1]), e2 = EX(sA[2]), e3 = EX(sA[3]);
            const float f0 = EX(sB[0]), f1 = EX(sB[1]), f2 = EX(sB[2]), f3 = EX(sB[3]);
            l += (e0 + e1 + e2 + e3) + (f0 + f1 + f2 + f3);
            bf16x4 wa = {(bf16)e0, (bf16)e1, (bf16)e2, (bf16)e3};
            bf16x4 wb = {(bf16)f0, (bf16)f1, (bf16)f2, (bf16)f3};
            *(bf16x4*)(Pw + qr * PLD + quad * 4)      = wa;
            *(bf16x4*)(Pw + qr * PLD + 16 + quad * 4) = wb;
        } else {
            const int qrow = qrow0 + qr;
            const int ka = t * 32 + quad * 4;
            const float e0 = (ka + 0  <= qrow) ? EX(sA[0]) : 0.f;
            const float e1 = (ka + 1  <= qrow) ? EX(sA[1]) : 0.f;
            const float e2 = (ka + 2  <= qrow) ? EX(sA[2]) : 0.f;
            const float e3 = (ka + 3  <= qrow) ? EX(sA[3]) : 0.f;
            const float f0 = (ka + 16 <= qrow) ? EX(sB[0]) : 0.f;
            const float f1 = (ka + 17 <= qrow) ? EX(sB[1]) : 0.f;
            const float f2 = (ka + 18 <= qrow) ? EX(sB[2]) : 0.f;
            const float f3 = (ka + 19 <= qrow) ? EX(sB[3]) : 0.f;
            l += (e0 + e1 + e2 + e3) + (f0 + f1 + f2 + f3);
            bf16x4 wa = {(bf16)e0, (bf16)e1, (bf16)e2, (bf16)e3};
            bf16x4 wb = {(bf16)f0, (bf16)f1, (bf16)f2, (bf16)f3};
            *(bf16x4*)(Pw + qr * PLD + quad * 4)      = wa;
            *(bf16x4*)(Pw + qr * PLD + 16 + quad * 4) = wb;
        }

        const bf16x8 pf = *(const bf16x8*)(Pw + qr * PLD + quad * 8);
        __builtin_amdgcn_s_setprio(1);
        o0 = MFMA(v0, pf, o0); o1 = MFMA(v1, pf, o1);
        o2 = MFMA(v2, pf, o2); o3 = MFMA(v3, pf, o3);
        __builtin_amdgcn_s_setprio(0);

        __syncthreads();    // all waves done with buf[cur]; buf[cur^1] staged
    }
#undef STAGE

    // row sum of l across the 4 quads holding this row's k-partials
    l += __shfl_xor(l, 16); l += __shfl_xor(l, 32);
    const float n = 1.f / l;

    // o_vi C-layout: row(dh within tile) = quad*4+reg, col(q row) = qr
    const int s_ = qrow0 + qr;
    bf16* cp = ctx + ((size_t)s_ * BATCH_N + b) * DM + h * HDIM + quad * 4;
    #define CW(ov, vi_) do { \
        bf16x4 cc = {(bf16)(ov[0] * n), (bf16)(ov[1] * n), \
                     (bf16)(ov[2] * n), (bf16)(ov[3] * n)}; \
        *(bf16x4*)(cp + (vi_) * 16) = cc; \
    } while (0)
    CW(o0, 0); CW(o1, 1); CW(o2, 2); CW(o3, 3);
    #undef CW
}

// ---------------------------------------------------------------------------
// Output projection: ctx(4096x1024 bf16) @ out_w^T + out_b -> d_out f32 [s][b][d]
// Rows-fastest grid (r10). Keeps the 128^2 tile: 256 blocks = 1/CU; a 256-row
// tile would leave half the CUs idle at this grid.
// ---------------------------------------------------------------------------
__global__ __launch_bounds__(256)
void proj_kernel(const bf16* __restrict__ X, const bf16* __restrict__ W,
                 const float* __restrict__ bias, float* __restrict__ out) {
    const int row0 = blockIdx.x * 128;      // fastest dim = rows
    const int col0 = blockIdx.y * 128;
    f32x4 acc[4][4];
    gemm_tile(X, W, row0, col0, DM, acc);

    const int lane = threadIdx.x & 63;
    const int wave = threadIdx.x >> 6;
    const int wr = wave >> 1, wc = wave & 1;
    const int qr = lane & 15, quad = lane >> 4;

    #pragma unroll
    for (int ni = 0; ni < 4; ++ni) {
        const int n = col0 + wc * 64 + ni * 16 + qr;
        const float bn = bias[n];
        #pragma unroll
        for (int mi = 0; mi < 4; ++mi) {
            #pragma unroll
            for (int r = 0; r < 4; ++r) {
                const int i = row0 + wr * 64 + mi * 16 + quad * 4 + r;
                out[(size_t)i * DM + n] = acc[mi][ni][r] + bn;
            }
        }
    }
}

extern "C" void kernel_launch(void* const* d_in, const int* in_sizes, int n_in,
                              void* d_out, int out_size, void* d_ws, size_t ws_size,
                              hipStream_t stream) {
    (void)in_sizes; (void)n_in; (void)out_size; (void)ws_size;
    const float* query = (const float*)d_in[0];
    const float* q_w   = (const float*)d_in[1];
    const float* q_b   = (const float*)d_in[2];
    const float* k_w   = (const float*)d_in[3];
    const float* k_b   = (const float*)d_in[4];
    const float* v_w   = (const float*)d_in[5];
    const float* v_b   = (const float*)d_in[6];
    const float* out_w = (const float*)d_in[7];
    const float* out_b = (const float*)d_in[8];
    // d_in[9] = attn_mask: deterministic causal -> recomputed in-kernel.

    // Workspace layout (peak 48 MB). Xb/Wqkv are dead after qkv_kernel.
    char* ws = (char*)d_ws;
    bf16*  Qb   = (bf16*)(ws);                        //  0..8   [b][h][s][dh]
    bf16*  Kb   = (bf16*)(ws + ((size_t)8  << 20));   //  8..16  [b][h][s][dh]
    bf16*  Vt   = (bf16*)(ws + ((size_t)16 << 20));   // 16..24  [b][h][dh][s]
    bf16*  ctx  = (bf16*)(ws + ((size_t)24 << 20));   // 24..32  [s*B+b][1024]
    bf16*  Wob  = (bf16*)(ws + ((size_t)32 << 20));   // 32..34
    bf16*  Xb   = (bf16*)(ws + ((size_t)34 << 20));   // 34..42 (dead after qkv)
    bf16*  Wqb  = (bf16*)(ws + ((size_t)42 << 20));   // 42..44 (dead after qkv)
    bf16*  Wkb  = (bf16*)(ws + ((size_t)44 << 20));   // 44..46 (dead after qkv)
    bf16*  Wvb  = (bf16*)(ws + ((size_t)46 << 20));   // 46..48 (dead after qkv)
    float* out  = (float*)d_out;

    dim3 blk(256);
    cvt_all<<<dim3(2048 + 4 * 512), blk, 0, stream>>>(
        query, q_w, k_w, v_w, out_w, Xb, Wqb, Wkb, Wvb, Wob);

    qkv_kernel<<<dim3((S_LEN * BATCH_N) / 256, DM / 128, 3), blk, 0, stream>>>(
        Xb, Wqb, q_b, Wkb, k_b, Wvb, v_b, Qb, Kb, Vt);
    attn_part<<<dim3(1024), blk, 0, stream>>>(Qb, Kb, Vt, ctx);
    proj_kernel<<<dim3((S_LEN * BATCH_N) / 128, DM / 128), blk, 0, stream>>>(
        ctx, Wob, out_b, out);
}

// Round 13
// 204.997 us; speedup vs baseline: 1.1047x; 1.1047x over previous
//
#include <hip/hip_runtime.h>
#include <hip/hip_bf16.h>

typedef __bf16 bf16;
typedef __attribute__((ext_vector_type(2))) __bf16 bf16x2;
typedef __attribute__((ext_vector_type(4))) __bf16 bf16x4;
typedef __attribute__((ext_vector_type(8))) __bf16 bf16x8;
typedef __attribute__((ext_vector_type(4))) float f32x4;

static_assert(sizeof(bf16x8) == 16, "bf16x8 must be 16B");

#define S_LEN 2048
#define BATCH_N 2
#define DM 1024
#define NHEAD 16
#define HDIM 64
#define LOG2E 1.44269504088896f

// async global->LDS, 16 B per lane. LDS dest: wave-uniform base + lane*16.
__device__ __forceinline__ void async_cp16(const void* g, void* l) {
    __builtin_amdgcn_global_load_lds(
        (const __attribute__((address_space(1))) void*)g,
        (__attribute__((address_space(3))) void*)l, 16, 0, 0);
}

// ---------------------------------------------------------------------------
// Fused f32 -> bf16 convert for all 5 tensors in ONE dispatch.
// ---------------------------------------------------------------------------
__global__ __launch_bounds__(256)
void cvt_all(const float* __restrict__ q,
             const float* __restrict__ w0, const float* __restrict__ w1,
             const float* __restrict__ w2, const float* __restrict__ w3,
             bf16* __restrict__ Xb,
             bf16* __restrict__ W0, bf16* __restrict__ W1,
             bf16* __restrict__ W2, bf16* __restrict__ W3) {
    const int blk = blockIdx.x;
    const float* src;
    bf16* dst;
    size_t base;
    if (blk < 2048) {
        src = q; dst = Xb; base = (size_t)blk * 2048;
    } else {
        const int w = (blk - 2048) >> 9;
        const int r = (blk - 2048) & 511;
        base = (size_t)r * 2048;
        src = (w == 0) ? w0 : (w == 1) ? w1 : (w == 2) ? w2 : w3;
        dst = (w == 0) ? W0 : (w == 1) ? W1 : (w == 2) ? W2 : W3;
    }
    const size_t i = base + (size_t)threadIdx.x * 8;
    const f32x4 a = *(const f32x4*)(src + i);
    const f32x4 b = *(const f32x4*)(src + i + 4);
    bf16x8 r8;
    r8[0] = (bf16)a[0]; r8[1] = (bf16)a[1]; r8[2] = (bf16)a[2]; r8[3] = (bf16)a[3];
    r8[4] = (bf16)b[0]; r8[5] = (bf16)b[1]; r8[6] = (bf16)b[2]; r8[7] = (bf16)b[3];
    *(bf16x8*)(dst + i) = r8;
}

// ---------------------------------------------------------------------------
// 128x128 bf16 MFMA GEMM tile: C = A * W^T. r8/r10 form (2-phase dbuf,
// __syncthreads). Best measured for qkv at this shape: 46.6 µs. The r11
// 256x128 variant collapsed occupancy (grid 384 = 1.5 blocks/CU): 60.5 µs.
// ---------------------------------------------------------------------------
__device__ __forceinline__ void gemm_tile(const bf16* __restrict__ A,
                                          const bf16* __restrict__ W,
                                          int row0, int col0, int Kdim,
                                          f32x4 acc[4][4]) {
    __shared__ bf16 As[2][128 * 32];
    __shared__ bf16 Bs[2][128 * 32];
    const int tid  = threadIdx.x;
    const int lane = tid & 63;
    const int wv   = tid >> 6;
    const int wr = wv >> 1, wc = wv & 1;
    const int qr = lane & 15, quad = lane >> 4;

    const int srow = wv * 16 + (lane >> 2);
    const int scol = (lane & 3) * 8;
    const bf16* Ap = A + (size_t)(row0 + srow) * Kdim + scol;
    const bf16* Wp = W + (size_t)(col0 + srow) * Kdim + scol;

    const f32x4 fzero = {0.f, 0.f, 0.f, 0.f};
    #pragma unroll
    for (int mi = 0; mi < 4; ++mi)
        #pragma unroll
        for (int ni = 0; ni < 4; ++ni)
            acc[mi][ni] = fzero;

#define GSTAGE(k0_, bi_) do { \
    async_cp16(Ap + (k0_),                       As[bi_] + wv * 512); \
    async_cp16(Ap + (size_t)64 * Kdim + (k0_),   As[bi_] + 64 * 32 + wv * 512); \
    async_cp16(Wp + (k0_),                       Bs[bi_] + wv * 512); \
    async_cp16(Wp + (size_t)64 * Kdim + (k0_),   Bs[bi_] + 64 * 32 + wv * 512); \
} while (0)

    const int nsteps = Kdim >> 5;
    GSTAGE(0, 0);
    __syncthreads();

    int cur = 0;
    for (int s = 0; s < nsteps; ++s) {
        if (s + 1 < nsteps) GSTAGE((s + 1) << 5, cur ^ 1);

        bf16x8 af[4], bfr[4];
        #pragma unroll
        for (int mi = 0; mi < 4; ++mi)
            af[mi] = *(const bf16x8*)(As[cur] + (wr * 64 + mi * 16 + qr) * 32 + quad * 8);
        #pragma unroll
        for (int ni = 0; ni < 4; ++ni)
            bfr[ni] = *(const bf16x8*)(Bs[cur] + (wc * 64 + ni * 16 + qr) * 32 + quad * 8);
        #pragma unroll
        for (int mi = 0; mi < 4; ++mi)
            #pragma unroll
            for (int ni = 0; ni < 4; ++ni)
                acc[mi][ni] = __builtin_amdgcn_mfma_f32_16x16x32_bf16(
                    af[mi], bfr[ni], acc[mi][ni], 0, 0, 0);

        __syncthreads();
        cur ^= 1;
    }
#undef GSTAGE
}

// ---------------------------------------------------------------------------
// QKV projection; scatter to bf16 (r10 form — best measured).
// Grid (row 32, col 8, mat 3) rows-fastest: consecutive blocks share one
// 256 KB W-panel per XCD L2 (r10: FETCH 36 -> 28.8 MB).
//   Q  [b][h][s][dh]   pre-scaled by 0.125*log2(e)
//   K  [b][h][s][dh]
//   Vt [b][h][dh][s]
// ---------------------------------------------------------------------------
__global__ __launch_bounds__(256)
void qkv_kernel(const bf16* __restrict__ X,
                const bf16* __restrict__ Wq, const float* __restrict__ bq,
                const bf16* __restrict__ Wk, const float* __restrict__ bk,
                const bf16* __restrict__ Wv, const float* __restrict__ bv,
                bf16* __restrict__ Q, bf16* __restrict__ Kt, bf16* __restrict__ Vt) {
    const int mat  = blockIdx.z;
    const bf16*  W    = (mat == 0) ? Wq : (mat == 1) ? Wk : Wv;
    const float* bias = (mat == 0) ? bq : (mat == 1) ? bk : bv;
    const int row0 = blockIdx.x * 128;      // fastest dim = rows (share W-panel)
    const int col0 = blockIdx.y * 128;

    f32x4 acc[4][4];
    gemm_tile(X, W, row0, col0, DM, acc);

    const int lane = threadIdx.x & 63;
    const int wave = threadIdx.x >> 6;
    const int wr = wave >> 1, wc = wave & 1;
    const int qr = lane & 15, quad = lane >> 4;

    #pragma unroll
    for (int ni = 0; ni < 4; ++ni) {
        const int n  = col0 + wc * 64 + ni * 16 + qr;
        const float bn = bias[n];
        const int h = n >> 6, dh = n & 63;
        #pragma unroll
        for (int mi = 0; mi < 4; ++mi) {
            const int i0 = row0 + wr * 64 + mi * 16 + quad * 4;   // even
            const float v0 = acc[mi][ni][0] + bn;
            const float v1 = acc[mi][ni][1] + bn;
            const float v2 = acc[mi][ni][2] + bn;
            const float v3 = acc[mi][ni][3] + bn;
            if (mat == 2) {
                const int s0 = i0 >> 1;                           // even too
                bf16x2 e0 = {(bf16)v0, (bf16)v2};                 // b = 0
                bf16x2 e1 = {(bf16)v1, (bf16)v3};                 // b = 1
                *(bf16x2*)(Vt + ((size_t)h * HDIM + dh) * S_LEN + s0) = e0;
                *(bf16x2*)(Vt + ((size_t)(NHEAD + h) * HDIM + dh) * S_LEN + s0) = e1;
            } else {
                #pragma unroll
                for (int r = 0; r < 4; ++r) {
                    const int i = i0 + r;
                    const int s = i >> 1, b = i & 1;
                    const float v = (r == 0) ? v0 : (r == 1) ? v1 : (r == 2) ? v2 : v3;
                    if (mat == 0) {
                        Q[((size_t)(b * NHEAD + h) * S_LEN + s) * HDIM + dh] =
                            (bf16)(v * (0.125f * LOG2E));
                    } else {
                        Kt[((size_t)(b * NHEAD + h) * S_LEN + s) * HDIM + dh] = (bf16)v;
                    }
                }
            }
        }
    }
}

// ---------------------------------------------------------------------------
// Single-stage fused causal attention, split-M waves + LDS-staged K/V,
// PAIR-PROCESSED k-tiles (2 tiles per barrier interval — m168-class lever).
// WHY: r10 arithmetic: 4 blocks/CU x ~33 serial tiles over 44.4 µs = ~3230
// cyc/tile vs ~1250 cyc of issue work — slack is the per-tile barrier + the
// serial QK->exp->P-bounce->PV chain. Pairing halves barriers (66->33) and
// doubles per-interval ILP (both tiles' QK MFMAs issue together; tile B's
// exp hides tile A's P-bounce).
// Grid 1024: bh = idx&31 (XCD-locks each bh's K/V set), balanced qb map:
// j = idx>>5, qb = (j<16)?31-j:j-16 -> every CU gets exactly 66 pairs.
// ntiles = 2qb+2 is even; ONLY the last pair (p==qb) is causal-masked.
// Single P buffer per wave: per-wave DS ops execute in order (and the
// compiler cannot disprove aliasing between the P writes/reads, so program
// order is preserved) -> Pread(A) -> Pwrite(B) at the same address is safe.
// LDS = K dbuf 2x8192 + V dbuf 2x8192 + P 4x1280 = 37888 B -> 4 blocks/CU.
// Swizzle rule 21: linear LDS dest + inv-swizzled global src + swizzled read.
// ---------------------------------------------------------------------------
#define PLD 40        // P row stride (bf16)
#define PT  640       // 16*PLD elems per wave

#define MFMA(a, b, c) __builtin_amdgcn_mfma_f32_16x16x32_bf16(a, b, c, 0, 0, 0)
#define EX(x) __builtin_amdgcn_exp2f(x)

__global__ __launch_bounds__(256)
void attn_part(const bf16* __restrict__ Q, const bf16* __restrict__ K,
               const bf16* __restrict__ Vt, bf16* __restrict__ ctx) {
    __shared__ __align__(16) char smem[37888];
    const int tid  = threadIdx.x;
    const int lane = tid & 63;
    const int wave = tid >> 6;
    const int qr = lane & 15, quad = lane >> 4;
    const int bh = blockIdx.x & 31;     // XCD = (blockIdx.x % 8) = bh % 8
    const int j  = blockIdx.x >> 5;
    const int b = bh >> 4, h = bh & 15;

    const char* Kg = (const char*)(K  + (size_t)bh * S_LEN * HDIM);
    const char* Vg = (const char*)(Vt + (size_t)bh * HDIM * S_LEN);
    const bf16* Qb = Q + (size_t)bh * S_LEN * HDIM;
    char* Ksm = smem;                   // 2 x 8192 (pair = two 4 KB tiles)
    char* Vsm = smem + 16384;           // 2 x 8192
    bf16* Pw  = (bf16*)(smem + 32768) + wave * PT;
    const f32x4 fzero = {0.f, 0.f, 0.f, 0.f};

    const int qb     = (j < 16) ? (31 - j) : (j - 16);   // balanced pairing
    const int qb0    = qb * 64;
    const int npairs = qb + 1;          // tiles 0..2qb+1, two per pair

    // staging addresses (thread-constant): LDS dest linear, source inv-swizzled
    const int d16   = tid * 16;
    const int ksrow = d16 >> 7;                               // K tile row 0..31
    const int ksoff = (d16 & 127) ^ ((ksrow & 7) << 4);
    const int vsrow = d16 >> 6;                               // V tile row 0..63
    const int vsoff = (d16 & 63) ^ ((vsrow & 3) << 4);
    const size_t kgbase = (size_t)ksrow * 128 + ksoff;
    const size_t vgbase = (size_t)vsrow * (S_LEN * 2) + vsoff;

#define STAGE_PAIR(p_, bi_) do { \
    async_cp16(Kg + (size_t)(2*(p_))     * 4096 + kgbase, Ksm + (bi_) * 8192 + wave * 1024); \
    async_cp16(Kg + (size_t)(2*(p_) + 1) * 4096 + kgbase, Ksm + (bi_) * 8192 + 4096 + wave * 1024); \
    async_cp16(Vg + (size_t)(2*(p_))     * 64 + vgbase,   Vsm + (bi_) * 8192 + wave * 1024); \
    async_cp16(Vg + (size_t)(2*(p_) + 1) * 64 + vgbase,   Vsm + (bi_) * 8192 + 4096 + wave * 1024); \
} while (0)

// full-softmax for one 32-k tile: sA_/sB_ -> wa_/wb_, accumulate l
#define SOFT_FULL(sA_, sB_, wa_, wb_) do { \
    const float e0 = EX(sA_[0]), e1 = EX(sA_[1]), e2 = EX(sA_[2]), e3 = EX(sA_[3]); \
    const float f0 = EX(sB_[0]), f1 = EX(sB_[1]), f2 = EX(sB_[2]), f3 = EX(sB_[3]); \
    l += (e0 + e1 + e2 + e3) + (f0 + f1 + f2 + f3); \
    wa_[0] = (bf16)e0; wa_[1] = (bf16)e1; wa_[2] = (bf16)e2; wa_[3] = (bf16)e3; \
    wb_[0] = (bf16)f0; wb_[1] = (bf16)f1; wb_[2] = (bf16)f2; wb_[3] = (bf16)f3; \
} while (0)

#define SOFT_MASK(sA_, sB_, wa_, wb_, t_) do { \
    const int qrow = qrow0 + qr; \
    const int ka = (t_) * 32 + quad * 4; \
    const float e0 = (ka + 0  <= qrow) ? EX(sA_[0]) : 0.f; \
    const float e1 = (ka + 1  <= qrow) ? EX(sA_[1]) : 0.f; \
    const float e2 = (ka + 2  <= qrow) ? EX(sA_[2]) : 0.f; \
    const float e3 = (ka + 3  <= qrow) ? EX(sA_[3]) : 0.f; \
    const float f0 = (ka + 16 <= qrow) ? EX(sB_[0]) : 0.f; \
    const float f1 = (ka + 17 <= qrow) ? EX(sB_[1]) : 0.f; \
    const float f2 = (ka + 18 <= qrow) ? EX(sB_[2]) : 0.f; \
    const float f3 = (ka + 19 <= qrow) ? EX(sB_[3]) : 0.f; \
    l += (e0 + e1 + e2 + e3) + (f0 + f1 + f2 + f3); \
    wa_[0] = (bf16)e0; wa_[1] = (bf16)e1; wa_[2] = (bf16)e2; wa_[3] = (bf16)e3; \
    wb_[0] = (bf16)f0; wb_[1] = (bf16)f1; wb_[2] = (bf16)f2; wb_[3] = (bf16)f3; \
} while (0)

    // this wave's 16 q rows
    const int qrow0 = qb0 + wave * 16;
    const bf16x8 qlo = *(const bf16x8*)(Qb + (size_t)(qrow0 + qr) * HDIM + quad * 8);
    const bf16x8 qhi = *(const bf16x8*)(Qb + (size_t)(qrow0 + qr) * HDIM + quad * 8 + 32);

    f32x4 o0 = fzero, o1 = fzero, o2 = fzero, o3 = fzero;
    float l = 0.f;

    STAGE_PAIR(0, 0);
    __syncthreads();

    const int sK = (qr & 7) << 4;
    const int sV = (qr & 3) << 4;

    for (int p = 0; p < npairs; ++p) {
        const int cur = p & 1;
        if (p + 1 < npairs) STAGE_PAIR(p + 1, cur ^ 1);

        const char* KcA = Ksm + cur * 8192;
        const char* KcB = KcA + 4096;
        const char* VcA = Vsm + cur * 8192;
        const char* VcB = VcA + 4096;

        const bf16x8 ka0 = *(const bf16x8*)(KcA + qr * 128        + ((quad * 16)      ^ sK));
        const bf16x8 ka1 = *(const bf16x8*)(KcA + qr * 128        + ((quad * 16 + 64) ^ sK));
        const bf16x8 ka2 = *(const bf16x8*)(KcA + (16 + qr) * 128 + ((quad * 16)      ^ sK));
        const bf16x8 ka3 = *(const bf16x8*)(KcA + (16 + qr) * 128 + ((quad * 16 + 64) ^ sK));
        const bf16x8 kb0 = *(const bf16x8*)(KcB + qr * 128        + ((quad * 16)      ^ sK));
        const bf16x8 kb1 = *(const bf16x8*)(KcB + qr * 128        + ((quad * 16 + 64) ^ sK));
        const bf16x8 kb2 = *(const bf16x8*)(KcB + (16 + qr) * 128 + ((quad * 16)      ^ sK));
        const bf16x8 kb3 = *(const bf16x8*)(KcB + (16 + qr) * 128 + ((quad * 16 + 64) ^ sK));
        const bf16x8 va0 = *(const bf16x8*)(VcA + qr * 64         + ((quad * 16) ^ sV));
        const bf16x8 va1 = *(const bf16x8*)(VcA + (16 + qr) * 64  + ((quad * 16) ^ sV));
        const bf16x8 va2 = *(const bf16x8*)(VcA + (32 + qr) * 64  + ((quad * 16) ^ sV));
        const bf16x8 va3 = *(const bf16x8*)(VcA + (48 + qr) * 64  + ((quad * 16) ^ sV));
        const bf16x8 vb0 = *(const bf16x8*)(VcB + qr * 64         + ((quad * 16) ^ sV));
        const bf16x8 vb1 = *(const bf16x8*)(VcB + (16 + qr) * 64  + ((quad * 16) ^ sV));
        const bf16x8 vb2 = *(const bf16x8*)(VcB + (32 + qr) * 64  + ((quad * 16) ^ sV));
        const bf16x8 vb3 = *(const bf16x8*)(VcB + (48 + qr) * 64  + ((quad * 16) ^ sV));

        // both tiles' QK back-to-back (8 MFMA, no interleaved LDS waits)
        f32x4 sA0 = MFMA(ka0, qlo, fzero); sA0 = MFMA(ka1, qhi, sA0);
        f32x4 sB0 = MFMA(ka2, qlo, fzero); sB0 = MFMA(ka3, qhi, sB0);
        f32x4 sA1 = MFMA(kb0, qlo, fzero); sA1 = MFMA(kb1, qhi, sA1);
        f32x4 sB1 = MFMA(kb2, qlo, fzero); sB1 = MFMA(kb3, qhi, sB1);

        bf16x4 waA, wbA, waB, wbB;
        if (p < qb) {
            SOFT_FULL(sA0, sB0, waA, wbA);
            SOFT_FULL(sA1, sB1, waB, wbB);
        } else {
            SOFT_MASK(sA0, sB0, waA, wbA, 2 * p);
            SOFT_MASK(sA1, sB1, waB, wbB, 2 * p + 1);
        }

        // tile A P-bounce + PV; tile B's exp/pack already in regs above
        *(bf16x4*)(Pw + qr * PLD + quad * 4)      = waA;
        *(bf16x4*)(Pw + qr * PLD + 16 + quad * 4) = wbA;
        const bf16x8 pfA = *(const bf16x8*)(Pw + qr * PLD + quad * 8);
        __builtin_amdgcn_s_setprio(1);
        o0 = MFMA(va0, pfA, o0); o1 = MFMA(va1, pfA, o1);
        o2 = MFMA(va2, pfA, o2); o3 = MFMA(va3, pfA, o3);
        __builtin_amdgcn_s_setprio(0);

        // tile B reuses the same P slot (per-wave DS ops are in-order)
        *(bf16x4*)(Pw + qr * PLD + quad * 4)      = waB;
        *(bf16x4*)(Pw + qr * PLD + 16 + quad * 4) = wbB;
        const bf16x8 pfB = *(const bf16x8*)(Pw + qr * PLD + quad * 8);
        __builtin_amdgcn_s_setprio(1);
        o0 = MFMA(vb0, pfB, o0); o1 = MFMA(vb1, pfB, o1);
        o2 = MFMA(vb2, pfB, o2); o3 = MFMA(vb3, pfB, o3);
        __builtin_amdgcn_s_setprio(0);

        __syncthreads();    // buf[cur] readers done; buf[cur^1] staged
    }
#undef STAGE_PAIR
#undef SOFT_FULL
#undef SOFT_MASK

    // row sum of l across the 4 quads holding this row's k-partials
    l += __shfl_xor(l, 16); l += __shfl_xor(l, 32);
    const float n = 1.f / l;

    // o_vi C-layout: row(dh within tile) = quad*4+reg, col(q row) = qr
    const int s_ = qrow0 + qr;
    bf16* cp = ctx + ((size_t)s_ * BATCH_N + b) * DM + h * HDIM + quad * 4;
    #define CW(ov, vi_) do { \
        bf16x4 cc = {(bf16)(ov[0] * n), (bf16)(ov[1] * n), \
                     (bf16)(ov[2] * n), (bf16)(ov[3] * n)}; \
        *(bf16x4*)(cp + (vi_) * 16) = cc; \
    } while (0)
    CW(o0, 0); CW(o1, 1); CW(o2, 2); CW(o3, 3);
    #undef CW
}

// ---------------------------------------------------------------------------
// Output projection: ctx(4096x1024 bf16) @ out_w^T + out_b -> d_out f32 [s][b][d]
// Rows-fastest grid (r10): consecutive blocks share the Wo panel in L2.
// ---------------------------------------------------------------------------
__global__ __launch_bounds__(256)
void proj_kernel(const bf16* __restrict__ X, const bf16* __restrict__ W,
                 const float* __restrict__ bias, float* __restrict__ out) {
    const int row0 = blockIdx.x * 128;      // fastest dim = rows
    const int col0 = blockIdx.y * 128;
    f32x4 acc[4][4];
    gemm_tile(X, W, row0, col0, DM, acc);

    const int lane = threadIdx.x & 63;
    const int wave = threadIdx.x >> 6;
    const int wr = wave >> 1, wc = wave & 1;
    const int qr = lane & 15, quad = lane >> 4;

    #pragma unroll
    for (int ni = 0; ni < 4; ++ni) {
        const int n = col0 + wc * 64 + ni * 16 + qr;
        const float bn = bias[n];
        #pragma unroll
        for (int mi = 0; mi < 4; ++mi) {
            #pragma unroll
            for (int r = 0; r < 4; ++r) {
                const int i = row0 + wr * 64 + mi * 16 + quad * 4 + r;
                out[(size_t)i * DM + n] = acc[mi][ni][r] + bn;
            }
        }
    }
}

extern "C" void kernel_launch(void* const* d_in, const int* in_sizes, int n_in,
                              void* d_out, int out_size, void* d_ws, size_t ws_size,
                              hipStream_t stream) {
    (void)in_sizes; (void)n_in; (void)out_size; (void)ws_size;
    const float* query = (const float*)d_in[0];
    const float* q_w   = (const float*)d_in[1];
    const float* q_b   = (const float*)d_in[2];
    const float* k_w   = (const float*)d_in[3];
    const float* k_b   = (const float*)d_in[4];
    const float* v_w   = (const float*)d_in[5];
    const float* v_b   = (const float*)d_in[6];
    const float* out_w = (const float*)d_in[7];
    const float* out_b = (const float*)d_in[8];
    // d_in[9] = attn_mask: deterministic causal -> recomputed in-kernel.

    // Workspace layout (peak 48 MB). Xb/Wqkv are dead after qkv_kernel.
    char* ws = (char*)d_ws;
    bf16*  Qb   = (bf16*)(ws);                        //  0..8   [b][h][s][dh]
    bf16*  Kb   = (bf16*)(ws + ((size_t)8  << 20));   //  8..16  [b][h][s][dh]
    bf16*  Vt   = (bf16*)(ws + ((size_t)16 << 20));   // 16..24  [b][h][dh][s]
    bf16*  ctx  = (bf16*)(ws + ((size_t)24 << 20));   // 24..32  [s*B+b][1024]
    bf16*  Wob  = (bf16*)(ws + ((size_t)32 << 20));   // 32..34
    bf16*  Xb   = (bf16*)(ws + ((size_t)34 << 20));   // 34..42 (dead after qkv)
    bf16*  Wqb  = (bf16*)(ws + ((size_t)42 << 20));   // 42..44 (dead after qkv)
    bf16*  Wkb  = (bf16*)(ws + ((size_t)44 << 20));   // 44..46 (dead after qkv)
    bf16*  Wvb  = (bf16*)(ws + ((size_t)46 << 20));   // 46..48 (dead after qkv)
    float* out  = (float*)d_out;

    dim3 blk(256);
    cvt_all<<<dim3(2048 + 4 * 512), blk, 0, stream>>>(
        query, q_w, k_w, v_w, out_w, Xb, Wqb, Wkb, Wvb, Wob);

    qkv_kernel<<<dim3((S_LEN * BATCH_N) / 128, DM / 128, 3), blk, 0, stream>>>(
        Xb, Wqb, q_b, Wkb, k_b, Wvb, v_b, Qb, Kb, Vt);
    attn_part<<<dim3(1024), blk, 0, stream>>>(Qb, Kb, Vt, ctx);
    proj_kernel<<<dim3((S_LEN * BATCH_N) / 128, DM / 128), blk, 0, stream>>>(
        ctx, Wob, out_b, out);
}

// Round 14
// 199.549 us; speedup vs baseline: 1.1348x; 1.0273x over previous
//
#include <hip/hip_runtime.h>
#include <hip/hip_bf16.h>

typedef __bf16 bf16;
typedef __attribute__((ext_vector_type(2))) __bf16 bf16x2;
typedef __attribute__((ext_vector_type(4))) __bf16 bf16x4;
typedef __attribute__((ext_vector_type(8))) __bf16 bf16x8;
typedef __attribute__((ext_vector_type(4))) float f32x4;

static_assert(sizeof(bf16x8) == 16, "bf16x8 must be 16B");

#define S_LEN 2048
#define BATCH_N 2
#define DM 1024
#define NHEAD 16
#define HDIM 64
#define LOG2E 1.44269504088896f

// async global->LDS, 16 B per lane. LDS dest: wave-uniform base + lane*16.
__device__ __forceinline__ void async_cp16(const void* g, void* l) {
    __builtin_amdgcn_global_load_lds(
        (const __attribute__((address_space(1))) void*)g,
        (__attribute__((address_space(3))) void*)l, 16, 0, 0);
}

// ---------------------------------------------------------------------------
// Fused f32 -> bf16 convert for all 5 tensors in ONE dispatch.
// ---------------------------------------------------------------------------
__global__ __launch_bounds__(256)
void cvt_all(const float* __restrict__ q,
             const float* __restrict__ w0, const float* __restrict__ w1,
             const float* __restrict__ w2, const float* __restrict__ w3,
             bf16* __restrict__ Xb,
             bf16* __restrict__ W0, bf16* __restrict__ W1,
             bf16* __restrict__ W2, bf16* __restrict__ W3) {
    const int blk = blockIdx.x;
    const float* src;
    bf16* dst;
    size_t base;
    if (blk < 2048) {
        src = q; dst = Xb; base = (size_t)blk * 2048;
    } else {
        const int w = (blk - 2048) >> 9;
        const int r = (blk - 2048) & 511;
        base = (size_t)r * 2048;
        src = (w == 0) ? w0 : (w == 1) ? w1 : (w == 2) ? w2 : w3;
        dst = (w == 0) ? W0 : (w == 1) ? W1 : (w == 2) ? W2 : W3;
    }
    const size_t i = base + (size_t)threadIdx.x * 8;
    const f32x4 a = *(const f32x4*)(src + i);
    const f32x4 b = *(const f32x4*)(src + i + 4);
    bf16x8 r8;
    r8[0] = (bf16)a[0]; r8[1] = (bf16)a[1]; r8[2] = (bf16)a[2]; r8[3] = (bf16)a[3];
    r8[4] = (bf16)b[0]; r8[5] = (bf16)b[1]; r8[6] = (bf16)b[2]; r8[7] = (bf16)b[3];
    *(bf16x8*)(dst + i) = r8;
}

// ---------------------------------------------------------------------------
// 128x128 bf16 MFMA GEMM tile (qkv): C = A * W^T. r8/r10 form (2-phase dbuf,
// __syncthreads). Best measured for qkv at this shape: ~45-47 µs band.
// ---------------------------------------------------------------------------
__device__ __forceinline__ void gemm_tile(const bf16* __restrict__ A,
                                          const bf16* __restrict__ W,
                                          int row0, int col0, int Kdim,
                                          f32x4 acc[4][4]) {
    __shared__ bf16 As[2][128 * 32];
    __shared__ bf16 Bs[2][128 * 32];
    const int tid  = threadIdx.x;
    const int lane = tid & 63;
    const int wv   = tid >> 6;
    const int wr = wv >> 1, wc = wv & 1;
    const int qr = lane & 15, quad = lane >> 4;

    const int srow = wv * 16 + (lane >> 2);
    const int scol = (lane & 3) * 8;
    const bf16* Ap = A + (size_t)(row0 + srow) * Kdim + scol;
    const bf16* Wp = W + (size_t)(col0 + srow) * Kdim + scol;

    const f32x4 fzero = {0.f, 0.f, 0.f, 0.f};
    #pragma unroll
    for (int mi = 0; mi < 4; ++mi)
        #pragma unroll
        for (int ni = 0; ni < 4; ++ni)
            acc[mi][ni] = fzero;

#define GSTAGE(k0_, bi_) do { \
    async_cp16(Ap + (k0_),                       As[bi_] + wv * 512); \
    async_cp16(Ap + (size_t)64 * Kdim + (k0_),   As[bi_] + 64 * 32 + wv * 512); \
    async_cp16(Wp + (k0_),                       Bs[bi_] + wv * 512); \
    async_cp16(Wp + (size_t)64 * Kdim + (k0_),   Bs[bi_] + 64 * 32 + wv * 512); \
} while (0)

    const int nsteps = Kdim >> 5;
    GSTAGE(0, 0);
    __syncthreads();

    int cur = 0;
    for (int s = 0; s < nsteps; ++s) {
        if (s + 1 < nsteps) GSTAGE((s + 1) << 5, cur ^ 1);

        bf16x8 af[4], bfr[4];
        #pragma unroll
        for (int mi = 0; mi < 4; ++mi)
            af[mi] = *(const bf16x8*)(As[cur] + (wr * 64 + mi * 16 + qr) * 32 + quad * 8);
        #pragma unroll
        for (int ni = 0; ni < 4; ++ni)
            bfr[ni] = *(const bf16x8*)(Bs[cur] + (wc * 64 + ni * 16 + qr) * 32 + quad * 8);
        #pragma unroll
        for (int mi = 0; mi < 4; ++mi)
            #pragma unroll
            for (int ni = 0; ni < 4; ++ni)
                acc[mi][ni] = __builtin_amdgcn_mfma_f32_16x16x32_bf16(
                    af[mi], bfr[ni], acc[mi][ni], 0, 0, 0);

        __syncthreads();
        cur ^= 1;
    }
#undef GSTAGE
}

// ---------------------------------------------------------------------------
// QKV projection; scatter to bf16 (r10 form — best measured).
// Grid (row 32, col 8, mat 3) rows-fastest: consecutive blocks share one
// 256 KB W-panel per XCD L2 (r10: FETCH 36 -> 28.8 MB).
//   Q  [b][h][s][dh]   pre-scaled by 0.125*log2(e)
//   K  [b][h][s][dh]
//   Vt [b][h][dh][s]
// ---------------------------------------------------------------------------
__global__ __launch_bounds__(256)
void qkv_kernel(const bf16* __restrict__ X,
                const bf16* __restrict__ Wq, const float* __restrict__ bq,
                const bf16* __restrict__ Wk, const float* __restrict__ bk,
                const bf16* __restrict__ Wv, const float* __restrict__ bv,
                bf16* __restrict__ Q, bf16* __restrict__ Kt, bf16* __restrict__ Vt) {
    const int mat  = blockIdx.z;
    const bf16*  W    = (mat == 0) ? Wq : (mat == 1) ? Wk : Wv;
    const float* bias = (mat == 0) ? bq : (mat == 1) ? bk : bv;
    const int row0 = blockIdx.x * 128;      // fastest dim = rows (share W-panel)
    const int col0 = blockIdx.y * 128;

    f32x4 acc[4][4];
    gemm_tile(X, W, row0, col0, DM, acc);

    const int lane = threadIdx.x & 63;
    const int wave = threadIdx.x >> 6;
    const int wr = wave >> 1, wc = wave & 1;
    const int qr = lane & 15, quad = lane >> 4;

    #pragma unroll
    for (int ni = 0; ni < 4; ++ni) {
        const int n  = col0 + wc * 64 + ni * 16 + qr;
        const float bn = bias[n];
        const int h = n >> 6, dh = n & 63;
        #pragma unroll
        for (int mi = 0; mi < 4; ++mi) {
            const int i0 = row0 + wr * 64 + mi * 16 + quad * 4;   // even
            const float v0 = acc[mi][ni][0] + bn;
            const float v1 = acc[mi][ni][1] + bn;
            const float v2 = acc[mi][ni][2] + bn;
            const float v3 = acc[mi][ni][3] + bn;
            if (mat == 2) {
                const int s0 = i0 >> 1;                           // even too
                bf16x2 e0 = {(bf16)v0, (bf16)v2};                 // b = 0
                bf16x2 e1 = {(bf16)v1, (bf16)v3};                 // b = 1
                *(bf16x2*)(Vt + ((size_t)h * HDIM + dh) * S_LEN + s0) = e0;
                *(bf16x2*)(Vt + ((size_t)(NHEAD + h) * HDIM + dh) * S_LEN + s0) = e1;
            } else {
                #pragma unroll
                for (int r = 0; r < 4; ++r) {
                    const int i = i0 + r;
                    const int s = i >> 1, b = i & 1;
                    const float v = (r == 0) ? v0 : (r == 1) ? v1 : (r == 2) ? v2 : v3;
                    if (mat == 0) {
                        Q[((size_t)(b * NHEAD + h) * S_LEN + s) * HDIM + dh] =
                            (bf16)(v * (0.125f * LOG2E));
                    } else {
                        Kt[((size_t)(b * NHEAD + h) * S_LEN + s) * HDIM + dh] = (bf16)v;
                    }
                }
            }
        }
    }
}

// ---------------------------------------------------------------------------
// Single-stage fused causal attention, split-M waves + LDS-staged K/V,
// PAIR-PROCESSED k-tiles (r13: attn dropped out of top-5, < 45 µs).
// Grid 1024: bh = idx&31 (XCD-locks K/V), balanced qb map -> 66 pairs/CU.
// ---------------------------------------------------------------------------
#define PLD 40        // P row stride (bf16)
#define PT  640       // 16*PLD elems per wave

#define MFMA(a, b, c) __builtin_amdgcn_mfma_f32_16x16x32_bf16(a, b, c, 0, 0, 0)
#define EX(x) __builtin_amdgcn_exp2f(x)

__global__ __launch_bounds__(256)
void attn_part(const bf16* __restrict__ Q, const bf16* __restrict__ K,
               const bf16* __restrict__ Vt, bf16* __restrict__ ctx) {
    __shared__ __align__(16) char smem[37888];
    const int tid  = threadIdx.x;
    const int lane = tid & 63;
    const int wave = tid >> 6;
    const int qr = lane & 15, quad = lane >> 4;
    const int bh = blockIdx.x & 31;     // XCD = (blockIdx.x % 8) = bh % 8
    const int j  = blockIdx.x >> 5;
    const int b = bh >> 4, h = bh & 15;

    const char* Kg = (const char*)(K  + (size_t)bh * S_LEN * HDIM);
    const char* Vg = (const char*)(Vt + (size_t)bh * HDIM * S_LEN);
    const bf16* Qb = Q + (size_t)bh * S_LEN * HDIM;
    char* Ksm = smem;                   // 2 x 8192 (pair = two 4 KB tiles)
    char* Vsm = smem + 16384;           // 2 x 8192
    bf16* Pw  = (bf16*)(smem + 32768) + wave * PT;
    const f32x4 fzero = {0.f, 0.f, 0.f, 0.f};

    const int qb     = (j < 16) ? (31 - j) : (j - 16);   // balanced pairing
    const int qb0    = qb * 64;
    const int npairs = qb + 1;          // tiles 0..2qb+1, two per pair

    // staging addresses (thread-constant): LDS dest linear, source inv-swizzled
    const int d16   = tid * 16;
    const int ksrow = d16 >> 7;                               // K tile row 0..31
    const int ksoff = (d16 & 127) ^ ((ksrow & 7) << 4);
    const int vsrow = d16 >> 6;                               // V tile row 0..63
    const int vsoff = (d16 & 63) ^ ((vsrow & 3) << 4);
    const size_t kgbase = (size_t)ksrow * 128 + ksoff;
    const size_t vgbase = (size_t)vsrow * (S_LEN * 2) + vsoff;

#define STAGE_PAIR(p_, bi_) do { \
    async_cp16(Kg + (size_t)(2*(p_))     * 4096 + kgbase, Ksm + (bi_) * 8192 + wave * 1024); \
    async_cp16(Kg + (size_t)(2*(p_) + 1) * 4096 + kgbase, Ksm + (bi_) * 8192 + 4096 + wave * 1024); \
    async_cp16(Vg + (size_t)(2*(p_))     * 64 + vgbase,   Vsm + (bi_) * 8192 + wave * 1024); \
    async_cp16(Vg + (size_t)(2*(p_) + 1) * 64 + vgbase,   Vsm + (bi_) * 8192 + 4096 + wave * 1024); \
} while (0)

// full-softmax for one 32-k tile: sA_/sB_ -> wa_/wb_, accumulate l
#define SOFT_FULL(sA_, sB_, wa_, wb_) do { \
    const float e0 = EX(sA_[0]), e1 = EX(sA_[1]), e2 = EX(sA_[2]), e3 = EX(sA_[3]); \
    const float f0 = EX(sB_[0]), f1 = EX(sB_[1]), f2 = EX(sB_[2]), f3 = EX(sB_[3]); \
    l += (e0 + e1 + e2 + e3) + (f0 + f1 + f2 + f3); \
    wa_[0] = (bf16)e0; wa_[1] = (bf16)e1; wa_[2] = (bf16)e2; wa_[3] = (bf16)e3; \
    wb_[0] = (bf16)f0; wb_[1] = (bf16)f1; wb_[2] = (bf16)f2; wb_[3] = (bf16)f3; \
} while (0)

#define SOFT_MASK(sA_, sB_, wa_, wb_, t_) do { \
    const int qrow = qrow0 + qr; \
    const int ka = (t_) * 32 + quad * 4; \
    const float e0 = (ka + 0  <= qrow) ? EX(sA_[0]) : 0.f; \
    const float e1 = (ka + 1  <= qrow) ? EX(sA_[1]) : 0.f; \
    const float e2 = (ka + 2  <= qrow) ? EX(sA_[2]) : 0.f; \
    const float e3 = (ka + 3  <= qrow) ? EX(sA_[3]) : 0.f; \
    const float f0 = (ka + 16 <= qrow) ? EX(sB_[0]) : 0.f; \
    const float f1 = (ka + 17 <= qrow) ? EX(sB_[1]) : 0.f; \
    const float f2 = (ka + 18 <= qrow) ? EX(sB_[2]) : 0.f; \
    const float f3 = (ka + 19 <= qrow) ? EX(sB_[3]) : 0.f; \
    l += (e0 + e1 + e2 + e3) + (f0 + f1 + f2 + f3); \
    wa_[0] = (bf16)e0; wa_[1] = (bf16)e1; wa_[2] = (bf16)e2; wa_[3] = (bf16)e3; \
    wb_[0] = (bf16)f0; wb_[1] = (bf16)f1; wb_[2] = (bf16)f2; wb_[3] = (bf16)f3; \
} while (0)

    // this wave's 16 q rows
    const int qrow0 = qb0 + wave * 16;
    const bf16x8 qlo = *(const bf16x8*)(Qb + (size_t)(qrow0 + qr) * HDIM + quad * 8);
    const bf16x8 qhi = *(const bf16x8*)(Qb + (size_t)(qrow0 + qr) * HDIM + quad * 8 + 32);

    f32x4 o0 = fzero, o1 = fzero, o2 = fzero, o3 = fzero;
    float l = 0.f;

    STAGE_PAIR(0, 0);
    __syncthreads();

    const int sK = (qr & 7) << 4;
    const int sV = (qr & 3) << 4;

    for (int p = 0; p < npairs; ++p) {
        const int cur = p & 1;
        if (p + 1 < npairs) STAGE_PAIR(p + 1, cur ^ 1);

        const char* KcA = Ksm + cur * 8192;
        const char* KcB = KcA + 4096;
        const char* VcA = Vsm + cur * 8192;
        const char* VcB = VcA + 4096;

        const bf16x8 ka0 = *(const bf16x8*)(KcA + qr * 128        + ((quad * 16)      ^ sK));
        const bf16x8 ka1 = *(const bf16x8*)(KcA + qr * 128        + ((quad * 16 + 64) ^ sK));
        const bf16x8 ka2 = *(const bf16x8*)(KcA + (16 + qr) * 128 + ((quad * 16)      ^ sK));
        const bf16x8 ka3 = *(const bf16x8*)(KcA + (16 + qr) * 128 + ((quad * 16 + 64) ^ sK));
        const bf16x8 kb0 = *(const bf16x8*)(KcB + qr * 128        + ((quad * 16)      ^ sK));
        const bf16x8 kb1 = *(const bf16x8*)(KcB + qr * 128        + ((quad * 16 + 64) ^ sK));
        const bf16x8 kb2 = *(const bf16x8*)(KcB + (16 + qr) * 128 + ((quad * 16)      ^ sK));
        const bf16x8 kb3 = *(const bf16x8*)(KcB + (16 + qr) * 128 + ((quad * 16 + 64) ^ sK));
        const bf16x8 va0 = *(const bf16x8*)(VcA + qr * 64         + ((quad * 16) ^ sV));
        const bf16x8 va1 = *(const bf16x8*)(VcA + (16 + qr) * 64  + ((quad * 16) ^ sV));
        const bf16x8 va2 = *(const bf16x8*)(VcA + (32 + qr) * 64  + ((quad * 16) ^ sV));
        const bf16x8 va3 = *(const bf16x8*)(VcA + (48 + qr) * 64  + ((quad * 16) ^ sV));
        const bf16x8 vb0 = *(const bf16x8*)(VcB + qr * 64         + ((quad * 16) ^ sV));
        const bf16x8 vb1 = *(const bf16x8*)(VcB + (16 + qr) * 64  + ((quad * 16) ^ sV));
        const bf16x8 vb2 = *(const bf16x8*)(VcB + (32 + qr) * 64  + ((quad * 16) ^ sV));
        const bf16x8 vb3 = *(const bf16x8*)(VcB + (48 + qr) * 64  + ((quad * 16) ^ sV));

        // both tiles' QK back-to-back (8 MFMA, no interleaved LDS waits)
        f32x4 sA0 = MFMA(ka0, qlo, fzero); sA0 = MFMA(ka1, qhi, sA0);
        f32x4 sB0 = MFMA(ka2, qlo, fzero); sB0 = MFMA(ka3, qhi, sB0);
        f32x4 sA1 = MFMA(kb0, qlo, fzero); sA1 = MFMA(kb1, qhi, sA1);
        f32x4 sB1 = MFMA(kb2, qlo, fzero); sB1 = MFMA(kb3, qhi, sB1);

        bf16x4 waA, wbA, waB, wbB;
        if (p < qb) {
            SOFT_FULL(sA0, sB0, waA, wbA);
            SOFT_FULL(sA1, sB1, waB, wbB);
        } else {
            SOFT_MASK(sA0, sB0, waA, wbA, 2 * p);
            SOFT_MASK(sA1, sB1, waB, wbB, 2 * p + 1);
        }

        // tile A P-bounce + PV; tile B's exp/pack already in regs above
        *(bf16x4*)(Pw + qr * PLD + quad * 4)      = waA;
        *(bf16x4*)(Pw + qr * PLD + 16 + quad * 4) = wbA;
        const bf16x8 pfA = *(const bf16x8*)(Pw + qr * PLD + quad * 8);
        __builtin_amdgcn_s_setprio(1);
        o0 = MFMA(va0, pfA, o0); o1 = MFMA(va1, pfA, o1);
        o2 = MFMA(va2, pfA, o2); o3 = MFMA(va3, pfA, o3);
        __builtin_amdgcn_s_setprio(0);

        // tile B reuses the same P slot (per-wave DS ops are in-order)
        *(bf16x4*)(Pw + qr * PLD + quad * 4)      = waB;
        *(bf16x4*)(Pw + qr * PLD + 16 + quad * 4) = wbB;
        const bf16x8 pfB = *(const bf16x8*)(Pw + qr * PLD + quad * 8);
        __builtin_amdgcn_s_setprio(1);
        o0 = MFMA(vb0, pfB, o0); o1 = MFMA(vb1, pfB, o1);
        o2 = MFMA(vb2, pfB, o2); o3 = MFMA(vb3, pfB, o3);
        __builtin_amdgcn_s_setprio(0);

        __syncthreads();    // buf[cur] readers done; buf[cur^1] staged
    }
#undef STAGE_PAIR
#undef SOFT_FULL
#undef SOFT_MASK

    // row sum of l across the 4 quads holding this row's k-partials
    l += __shfl_xor(l, 16); l += __shfl_xor(l, 32);
    const float n = 1.f / l;

    // o_vi C-layout: row(dh within tile) = quad*4+reg, col(q row) = qr
    const int s_ = qrow0 + qr;
    bf16* cp = ctx + ((size_t)s_ * BATCH_N + b) * DM + h * HDIM + quad * 4;
    #define CW(ov, vi_) do { \
        bf16x4 cc = {(bf16)(ov[0] * n), (bf16)(ov[1] * n), \
                     (bf16)(ov[2] * n), (bf16)(ov[3] * n)}; \
        *(bf16x4*)(cp + (vi_) * 16) = cc; \
    } while (0)
    CW(o0, 0); CW(o1, 1); CW(o2, 2); CW(o3, 3);
    #undef CW
}

// ---------------------------------------------------------------------------
// Output projection: ctx(4096x1024 bf16) @ out_w^T + out_b -> d_out f32 [s][b][d]
// 64x128 tile, grid (64 rows, 8 cols) = 512 blocks = 2 blocks/CU.
// WHY: the old 128^2 tile gave grid 256 = EXACTLY 1 block/CU (4 waves,
// 12.5% occupancy cap) — this 2-phase structure relies on cross-block
// overlap to hide the barrier drain (qkv runs 3 blocks/CU). Doubling
// blocks/CU costs LDS intensity (per-wave 32x64: 21.3 vs 32 FLOP/elem)
// but proj at <=2 blocks/CU is far from the LDS-throughput wall.
// Rows-fastest grid: consecutive blocks share the Wo panel in L2.
// ---------------------------------------------------------------------------
__global__ __launch_bounds__(256)
void proj_kernel(const bf16* __restrict__ X, const bf16* __restrict__ W,
                 const float* __restrict__ bias, float* __restrict__ out) {
    __shared__ bf16 As[2][64 * 32];     //  8 KB
    __shared__ bf16 Bs[2][128 * 32];    // 16 KB
    const int row0 = blockIdx.x * 64;       // fastest dim = rows
    const int col0 = blockIdx.y * 128;
    const int tid  = threadIdx.x;
    const int lane = tid & 63;
    const int wv   = tid >> 6;
    const int wr = wv >> 1, wc = wv & 1;
    const int qr = lane & 15, quad = lane >> 4;

    // staging: per 4 KB chunk (64 rows x 32 cols) thread covers 16 B:
    // row = tid>>2, col = (tid&3)*8; LDS elem tid*8 = row*32+col (row-major).
    const int sr = tid >> 2;
    const int sc = (tid & 3) * 8;
    const bf16* Ap = X + (size_t)(row0 + sr) * DM + sc;
    const bf16* Wp = W + (size_t)(col0 + sr) * DM + sc;

    const f32x4 fzero = {0.f, 0.f, 0.f, 0.f};
    f32x4 acc[2][4];
    #pragma unroll
    for (int mi = 0; mi < 2; ++mi)
        #pragma unroll
        for (int ni = 0; ni < 4; ++ni)
            acc[mi][ni] = fzero;

#define PSTAGE(k0_, bi_) do { \
    async_cp16(Ap + (k0_),                     As[bi_] + tid * 8); \
    async_cp16(Wp + (k0_),                     Bs[bi_] + tid * 8); \
    async_cp16(Wp + (size_t)64 * DM + (k0_),   Bs[bi_] + 2048 + tid * 8); \
} while (0)

    PSTAGE(0, 0);
    __syncthreads();

    int cur = 0;
    for (int s = 0; s < 32; ++s) {          // K = 1024, BK = 32
        if (s + 1 < 32) PSTAGE((s + 1) << 5, cur ^ 1);

        bf16x8 af[2], bfr[4];
        #pragma unroll
        for (int mi = 0; mi < 2; ++mi)
            af[mi] = *(const bf16x8*)(As[cur] + (wr * 32 + mi * 16 + qr) * 32 + quad * 8);
        #pragma unroll
        for (int ni = 0; ni < 4; ++ni)
            bfr[ni] = *(const bf16x8*)(Bs[cur] + (wc * 64 + ni * 16 + qr) * 32 + quad * 8);
        #pragma unroll
        for (int mi = 0; mi < 2; ++mi)
            #pragma unroll
            for (int ni = 0; ni < 4; ++ni)
                acc[mi][ni] = __builtin_amdgcn_mfma_f32_16x16x32_bf16(
                    af[mi], bfr[ni], acc[mi][ni], 0, 0, 0);

        __syncthreads();
        cur ^= 1;
    }
#undef PSTAGE

    #pragma unroll
    for (int ni = 0; ni < 4; ++ni) {
        const int n = col0 + wc * 64 + ni * 16 + qr;
        const float bn = bias[n];
        #pragma unroll
        for (int mi = 0; mi < 2; ++mi) {
            #pragma unroll
            for (int r = 0; r < 4; ++r) {
                const int i = row0 + wr * 32 + mi * 16 + quad * 4 + r;
                out[(size_t)i * DM + n] = acc[mi][ni][r] + bn;
            }
        }
    }
}

extern "C" void kernel_launch(void* const* d_in, const int* in_sizes, int n_in,
                              void* d_out, int out_size, void* d_ws, size_t ws_size,
                              hipStream_t stream) {
    (void)in_sizes; (void)n_in; (void)out_size; (void)ws_size;
    const float* query = (const float*)d_in[0];
    const float* q_w   = (const float*)d_in[1];
    const float* q_b   = (const float*)d_in[2];
    const float* k_w   = (const float*)d_in[3];
    const float* k_b   = (const float*)d_in[4];
    const float* v_w   = (const float*)d_in[5];
    const float* v_b   = (const float*)d_in[6];
    const float* out_w = (const float*)d_in[7];
    const float* out_b = (const float*)d_in[8];
    // d_in[9] = attn_mask: deterministic causal -> recomputed in-kernel.

    // Workspace layout (peak 48 MB). Xb/Wqkv are dead after qkv_kernel.
    char* ws = (char*)d_ws;
    bf16*  Qb   = (bf16*)(ws);                        //  0..8   [b][h][s][dh]
    bf16*  Kb   = (bf16*)(ws + ((size_t)8  << 20));   //  8..16  [b][h][s][dh]
    bf16*  Vt   = (bf16*)(ws + ((size_t)16 << 20));   // 16..24  [b][h][dh][s]
    bf16*  ctx  = (bf16*)(ws + ((size_t)24 << 20));   // 24..32  [s*B+b][1024]
    bf16*  Wob  = (bf16*)(ws + ((size_t)32 << 20));   // 32..34
    bf16*  Xb   = (bf16*)(ws + ((size_t)34 << 20));   // 34..42 (dead after qkv)
    bf16*  Wqb  = (bf16*)(ws + ((size_t)42 << 20));   // 42..44 (dead after qkv)
    bf16*  Wkb  = (bf16*)(ws + ((size_t)44 << 20));   // 44..46 (dead after qkv)
    bf16*  Wvb  = (bf16*)(ws + ((size_t)46 << 20));   // 46..48 (dead after qkv)
    float* out  = (float*)d_out;

    dim3 blk(256);
    cvt_all<<<dim3(2048 + 4 * 512), blk, 0, stream>>>(
        query, q_w, k_w, v_w, out_w, Xb, Wqb, Wkb, Wvb, Wob);

    qkv_kernel<<<dim3((S_LEN * BATCH_N) / 128, DM / 128, 3), blk, 0, stream>>>(
        Xb, Wqb, q_b, Wkb, k_b, Wvb, v_b, Qb, Kb, Vt);
    attn_part<<<dim3(1024), blk, 0, stream>>>(Qb, Kb, Vt, ctx);
    proj_kernel<<<dim3((S_LEN * BATCH_N) / 64, DM / 128), blk, 0, stream>>>(
        ctx, Wob, out_b, out);
}

// Round 15
// 198.435 us; speedup vs baseline: 1.1412x; 1.0056x over previous
//
#include <hip/hip_runtime.h>
#include <hip/hip_bf16.h>

typedef __bf16 bf16;
typedef __attribute__((ext_vector_type(2))) __bf16 bf16x2;
typedef __attribute__((ext_vector_type(4))) __bf16 bf16x4;
typedef __attribute__((ext_vector_type(8))) __bf16 bf16x8;
typedef __attribute__((ext_vector_type(4))) float f32x4;

static_assert(sizeof(bf16x8) == 16, "bf16x8 must be 16B");

#define S_LEN 2048
#define BATCH_N 2
#define DM 1024
#define NHEAD 16
#define HDIM 64
#define LOG2E 1.44269504088896f

// async global->LDS, 16 B per lane. LDS dest: wave-uniform base + lane*16.
__device__ __forceinline__ void async_cp16(const void* g, void* l) {
    __builtin_amdgcn_global_load_lds(
        (const __attribute__((address_space(1))) void*)g,
        (__attribute__((address_space(3))) void*)l, 16, 0, 0);
}

// ---------------------------------------------------------------------------
// Fused f32 -> bf16 convert for all 5 tensors in ONE dispatch.
// ---------------------------------------------------------------------------
__global__ __launch_bounds__(256)
void cvt_all(const float* __restrict__ q,
             const float* __restrict__ w0, const float* __restrict__ w1,
             const float* __restrict__ w2, const float* __restrict__ w3,
             bf16* __restrict__ Xb,
             bf16* __restrict__ W0, bf16* __restrict__ W1,
             bf16* __restrict__ W2, bf16* __restrict__ W3) {
    const int blk = blockIdx.x;
    const float* src;
    bf16* dst;
    size_t base;
    if (blk < 2048) {
        src = q; dst = Xb; base = (size_t)blk * 2048;
    } else {
        const int w = (blk - 2048) >> 9;
        const int r = (blk - 2048) & 511;
        base = (size_t)r * 2048;
        src = (w == 0) ? w0 : (w == 1) ? w1 : (w == 2) ? w2 : w3;
        dst = (w == 0) ? W0 : (w == 1) ? W1 : (w == 2) ? W2 : W3;
    }
    const size_t i = base + (size_t)threadIdx.x * 8;
    const f32x4 a = *(const f32x4*)(src + i);
    const f32x4 b = *(const f32x4*)(src + i + 4);
    bf16x8 r8;
    r8[0] = (bf16)a[0]; r8[1] = (bf16)a[1]; r8[2] = (bf16)a[2]; r8[3] = (bf16)a[3];
    r8[4] = (bf16)b[0]; r8[5] = (bf16)b[1]; r8[6] = (bf16)b[2]; r8[7] = (bf16)b[3];
    *(bf16x8*)(dst + i) = r8;
}

// ---------------------------------------------------------------------------
// 128x128 bf16 MFMA GEMM tile (qkv): C = A * W^T. r8/r10 form (2-phase dbuf,
// __syncthreads). Best measured for qkv at this shape: ~45-47 µs band.
// ---------------------------------------------------------------------------
__device__ __forceinline__ void gemm_tile(const bf16* __restrict__ A,
                                          const bf16* __restrict__ W,
                                          int row0, int col0, int Kdim,
                                          f32x4 acc[4][4]) {
    __shared__ bf16 As[2][128 * 32];
    __shared__ bf16 Bs[2][128 * 32];
    const int tid  = threadIdx.x;
    const int lane = tid & 63;
    const int wv   = tid >> 6;
    const int wr = wv >> 1, wc = wv & 1;
    const int qr = lane & 15, quad = lane >> 4;

    const int srow = wv * 16 + (lane >> 2);
    const int scol = (lane & 3) * 8;
    const bf16* Ap = A + (size_t)(row0 + srow) * Kdim + scol;
    const bf16* Wp = W + (size_t)(col0 + srow) * Kdim + scol;

    const f32x4 fzero = {0.f, 0.f, 0.f, 0.f};
    #pragma unroll
    for (int mi = 0; mi < 4; ++mi)
        #pragma unroll
        for (int ni = 0; ni < 4; ++ni)
            acc[mi][ni] = fzero;

#define GSTAGE(k0_, bi_) do { \
    async_cp16(Ap + (k0_),                       As[bi_] + wv * 512); \
    async_cp16(Ap + (size_t)64 * Kdim + (k0_),   As[bi_] + 64 * 32 + wv * 512); \
    async_cp16(Wp + (k0_),                       Bs[bi_] + wv * 512); \
    async_cp16(Wp + (size_t)64 * Kdim + (k0_),   Bs[bi_] + 64 * 32 + wv * 512); \
} while (0)

    const int nsteps = Kdim >> 5;
    GSTAGE(0, 0);
    __syncthreads();

    int cur = 0;
    for (int s = 0; s < nsteps; ++s) {
        if (s + 1 < nsteps) GSTAGE((s + 1) << 5, cur ^ 1);

        bf16x8 af[4], bfr[4];
        #pragma unroll
        for (int mi = 0; mi < 4; ++mi)
            af[mi] = *(const bf16x8*)(As[cur] + (wr * 64 + mi * 16 + qr) * 32 + quad * 8);
        #pragma unroll
        for (int ni = 0; ni < 4; ++ni)
            bfr[ni] = *(const bf16x8*)(Bs[cur] + (wc * 64 + ni * 16 + qr) * 32 + quad * 8);
        #pragma unroll
        for (int mi = 0; mi < 4; ++mi)
            #pragma unroll
            for (int ni = 0; ni < 4; ++ni)
                acc[mi][ni] = __builtin_amdgcn_mfma_f32_16x16x32_bf16(
                    af[mi], bfr[ni], acc[mi][ni], 0, 0, 0);

        __syncthreads();
        cur ^= 1;
    }
#undef GSTAGE
}

// ---------------------------------------------------------------------------
// QKV projection; scatter to bf16 (r10 form — best measured).
// Grid (row 32, col 8, mat 3) rows-fastest: consecutive blocks share one
// 256 KB W-panel per XCD L2 (r10: FETCH 36 -> 28.8 MB).
//   Q  [b][h][s][dh]   pre-scaled by 0.125*log2(e)
//   K  [b][h][s][dh]
//   Vt [b][h][dh][s]
// ---------------------------------------------------------------------------
__global__ __launch_bounds__(256)
void qkv_kernel(const bf16* __restrict__ X,
                const bf16* __restrict__ Wq, const float* __restrict__ bq,
                const bf16* __restrict__ Wk, const float* __restrict__ bk,
                const bf16* __restrict__ Wv, const float* __restrict__ bv,
                bf16* __restrict__ Q, bf16* __restrict__ Kt, bf16* __restrict__ Vt) {
    const int mat  = blockIdx.z;
    const bf16*  W    = (mat == 0) ? Wq : (mat == 1) ? Wk : Wv;
    const float* bias = (mat == 0) ? bq : (mat == 1) ? bk : bv;
    const int row0 = blockIdx.x * 128;      // fastest dim = rows (share W-panel)
    const int col0 = blockIdx.y * 128;

    f32x4 acc[4][4];
    gemm_tile(X, W, row0, col0, DM, acc);

    const int lane = threadIdx.x & 63;
    const int wave = threadIdx.x >> 6;
    const int wr = wave >> 1, wc = wave & 1;
    const int qr = lane & 15, quad = lane >> 4;

    #pragma unroll
    for (int ni = 0; ni < 4; ++ni) {
        const int n  = col0 + wc * 64 + ni * 16 + qr;
        const float bn = bias[n];
        const int h = n >> 6, dh = n & 63;
        #pragma unroll
        for (int mi = 0; mi < 4; ++mi) {
            const int i0 = row0 + wr * 64 + mi * 16 + quad * 4;   // even
            const float v0 = acc[mi][ni][0] + bn;
            const float v1 = acc[mi][ni][1] + bn;
            const float v2 = acc[mi][ni][2] + bn;
            const float v3 = acc[mi][ni][3] + bn;
            if (mat == 2) {
                const int s0 = i0 >> 1;                           // even too
                bf16x2 e0 = {(bf16)v0, (bf16)v2};                 // b = 0
                bf16x2 e1 = {(bf16)v1, (bf16)v3};                 // b = 1
                *(bf16x2*)(Vt + ((size_t)h * HDIM + dh) * S_LEN + s0) = e0;
                *(bf16x2*)(Vt + ((size_t)(NHEAD + h) * HDIM + dh) * S_LEN + s0) = e1;
            } else {
                #pragma unroll
                for (int r = 0; r < 4; ++r) {
                    const int i = i0 + r;
                    const int s = i >> 1, b = i & 1;
                    const float v = (r == 0) ? v0 : (r == 1) ? v1 : (r == 2) ? v2 : v3;
                    if (mat == 0) {
                        Q[((size_t)(b * NHEAD + h) * S_LEN + s) * HDIM + dh] =
                            (bf16)(v * (0.125f * LOG2E));
                    } else {
                        Kt[((size_t)(b * NHEAD + h) * S_LEN + s) * HDIM + dh] = (bf16)v;
                    }
                }
            }
        }
    }
}

// ---------------------------------------------------------------------------
// Single-stage fused causal attention, split-M waves + LDS-staged K/V,
// PAIR-PROCESSED k-tiles (r13: attn ~38 µs by delta accounting).
// Grid 1024: bh = idx&31 (XCD-locks K/V), balanced qb map -> 66 pairs/CU.
// ---------------------------------------------------------------------------
#define PLD 40        // P row stride (bf16)
#define PT  640       // 16*PLD elems per wave

#define MFMA(a, b, c) __builtin_amdgcn_mfma_f32_16x16x32_bf16(a, b, c, 0, 0, 0)
#define EX(x) __builtin_amdgcn_exp2f(x)

__global__ __launch_bounds__(256)
void attn_part(const bf16* __restrict__ Q, const bf16* __restrict__ K,
               const bf16* __restrict__ Vt, bf16* __restrict__ ctx) {
    __shared__ __align__(16) char smem[37888];
    const int tid  = threadIdx.x;
    const int lane = tid & 63;
    const int wave = tid >> 6;
    const int qr = lane & 15, quad = lane >> 4;
    const int bh = blockIdx.x & 31;     // XCD = (blockIdx.x % 8) = bh % 8
    const int j  = blockIdx.x >> 5;
    const int b = bh >> 4, h = bh & 15;

    const char* Kg = (const char*)(K  + (size_t)bh * S_LEN * HDIM);
    const char* Vg = (const char*)(Vt + (size_t)bh * HDIM * S_LEN);
    const bf16* Qb = Q + (size_t)bh * S_LEN * HDIM;
    char* Ksm = smem;                   // 2 x 8192 (pair = two 4 KB tiles)
    char* Vsm = smem + 16384;           // 2 x 8192
    bf16* Pw  = (bf16*)(smem + 32768) + wave * PT;
    const f32x4 fzero = {0.f, 0.f, 0.f, 0.f};

    const int qb     = (j < 16) ? (31 - j) : (j - 16);   // balanced pairing
    const int qb0    = qb * 64;
    const int npairs = qb + 1;          // tiles 0..2qb+1, two per pair

    // staging addresses (thread-constant): LDS dest linear, source inv-swizzled
    const int d16   = tid * 16;
    const int ksrow = d16 >> 7;                               // K tile row 0..31
    const int ksoff = (d16 & 127) ^ ((ksrow & 7) << 4);
    const int vsrow = d16 >> 6;                               // V tile row 0..63
    const int vsoff = (d16 & 63) ^ ((vsrow & 3) << 4);
    const size_t kgbase = (size_t)ksrow * 128 + ksoff;
    const size_t vgbase = (size_t)vsrow * (S_LEN * 2) + vsoff;

#define STAGE_PAIR(p_, bi_) do { \
    async_cp16(Kg + (size_t)(2*(p_))     * 4096 + kgbase, Ksm + (bi_) * 8192 + wave * 1024); \
    async_cp16(Kg + (size_t)(2*(p_) + 1) * 4096 + kgbase, Ksm + (bi_) * 8192 + 4096 + wave * 1024); \
    async_cp16(Vg + (size_t)(2*(p_))     * 64 + vgbase,   Vsm + (bi_) * 8192 + wave * 1024); \
    async_cp16(Vg + (size_t)(2*(p_) + 1) * 64 + vgbase,   Vsm + (bi_) * 8192 + 4096 + wave * 1024); \
} while (0)

// full-softmax for one 32-k tile: sA_/sB_ -> wa_/wb_, accumulate l
#define SOFT_FULL(sA_, sB_, wa_, wb_) do { \
    const float e0 = EX(sA_[0]), e1 = EX(sA_[1]), e2 = EX(sA_[2]), e3 = EX(sA_[3]); \
    const float f0 = EX(sB_[0]), f1 = EX(sB_[1]), f2 = EX(sB_[2]), f3 = EX(sB_[3]); \
    l += (e0 + e1 + e2 + e3) + (f0 + f1 + f2 + f3); \
    wa_[0] = (bf16)e0; wa_[1] = (bf16)e1; wa_[2] = (bf16)e2; wa_[3] = (bf16)e3; \
    wb_[0] = (bf16)f0; wb_[1] = (bf16)f1; wb_[2] = (bf16)f2; wb_[3] = (bf16)f3; \
} while (0)

#define SOFT_MASK(sA_, sB_, wa_, wb_, t_) do { \
    const int qrow = qrow0 + qr; \
    const int ka = (t_) * 32 + quad * 4; \
    const float e0 = (ka + 0  <= qrow) ? EX(sA_[0]) : 0.f; \
    const float e1 = (ka + 1  <= qrow) ? EX(sA_[1]) : 0.f; \
    const float e2 = (ka + 2  <= qrow) ? EX(sA_[2]) : 0.f; \
    const float e3 = (ka + 3  <= qrow) ? EX(sA_[3]) : 0.f; \
    const float f0 = (ka + 16 <= qrow) ? EX(sB_[0]) : 0.f; \
    const float f1 = (ka + 17 <= qrow) ? EX(sB_[1]) : 0.f; \
    const float f2 = (ka + 18 <= qrow) ? EX(sB_[2]) : 0.f; \
    const float f3 = (ka + 19 <= qrow) ? EX(sB_[3]) : 0.f; \
    l += (e0 + e1 + e2 + e3) + (f0 + f1 + f2 + f3); \
    wa_[0] = (bf16)e0; wa_[1] = (bf16)e1; wa_[2] = (bf16)e2; wa_[3] = (bf16)e3; \
    wb_[0] = (bf16)f0; wb_[1] = (bf16)f1; wb_[2] = (bf16)f2; wb_[3] = (bf16)f3; \
} while (0)

    // this wave's 16 q rows
    const int qrow0 = qb0 + wave * 16;
    const bf16x8 qlo = *(const bf16x8*)(Qb + (size_t)(qrow0 + qr) * HDIM + quad * 8);
    const bf16x8 qhi = *(const bf16x8*)(Qb + (size_t)(qrow0 + qr) * HDIM + quad * 8 + 32);

    f32x4 o0 = fzero, o1 = fzero, o2 = fzero, o3 = fzero;
    float l = 0.f;

    STAGE_PAIR(0, 0);
    __syncthreads();

    const int sK = (qr & 7) << 4;
    const int sV = (qr & 3) << 4;

    for (int p = 0; p < npairs; ++p) {
        const int cur = p & 1;
        if (p + 1 < npairs) STAGE_PAIR(p + 1, cur ^ 1);

        const char* KcA = Ksm + cur * 8192;
        const char* KcB = KcA + 4096;
        const char* VcA = Vsm + cur * 8192;
        const char* VcB = VcA + 4096;

        const bf16x8 ka0 = *(const bf16x8*)(KcA + qr * 128        + ((quad * 16)      ^ sK));
        const bf16x8 ka1 = *(const bf16x8*)(KcA + qr * 128        + ((quad * 16 + 64) ^ sK));
        const bf16x8 ka2 = *(const bf16x8*)(KcA + (16 + qr) * 128 + ((quad * 16)      ^ sK));
        const bf16x8 ka3 = *(const bf16x8*)(KcA + (16 + qr) * 128 + ((quad * 16 + 64) ^ sK));
        const bf16x8 kb0 = *(const bf16x8*)(KcB + qr * 128        + ((quad * 16)      ^ sK));
        const bf16x8 kb1 = *(const bf16x8*)(KcB + qr * 128        + ((quad * 16 + 64) ^ sK));
        const bf16x8 kb2 = *(const bf16x8*)(KcB + (16 + qr) * 128 + ((quad * 16)      ^ sK));
        const bf16x8 kb3 = *(const bf16x8*)(KcB + (16 + qr) * 128 + ((quad * 16 + 64) ^ sK));
        const bf16x8 va0 = *(const bf16x8*)(VcA + qr * 64         + ((quad * 16) ^ sV));
        const bf16x8 va1 = *(const bf16x8*)(VcA + (16 + qr) * 64  + ((quad * 16) ^ sV));
        const bf16x8 va2 = *(const bf16x8*)(VcA + (32 + qr) * 64  + ((quad * 16) ^ sV));
        const bf16x8 va3 = *(const bf16x8*)(VcA + (48 + qr) * 64  + ((quad * 16) ^ sV));
        const bf16x8 vb0 = *(const bf16x8*)(VcB + qr * 64         + ((quad * 16) ^ sV));
        const bf16x8 vb1 = *(const bf16x8*)(VcB + (16 + qr) * 64  + ((quad * 16) ^ sV));
        const bf16x8 vb2 = *(const bf16x8*)(VcB + (32 + qr) * 64  + ((quad * 16) ^ sV));
        const bf16x8 vb3 = *(const bf16x8*)(VcB + (48 + qr) * 64  + ((quad * 16) ^ sV));

        // both tiles' QK back-to-back (8 MFMA, no interleaved LDS waits)
        f32x4 sA0 = MFMA(ka0, qlo, fzero); sA0 = MFMA(ka1, qhi, sA0);
        f32x4 sB0 = MFMA(ka2, qlo, fzero); sB0 = MFMA(ka3, qhi, sB0);
        f32x4 sA1 = MFMA(kb0, qlo, fzero); sA1 = MFMA(kb1, qhi, sA1);
        f32x4 sB1 = MFMA(kb2, qlo, fzero); sB1 = MFMA(kb3, qhi, sB1);

        bf16x4 waA, wbA, waB, wbB;
        if (p < qb) {
            SOFT_FULL(sA0, sB0, waA, wbA);
            SOFT_FULL(sA1, sB1, waB, wbB);
        } else {
            SOFT_MASK(sA0, sB0, waA, wbA, 2 * p);
            SOFT_MASK(sA1, sB1, waB, wbB, 2 * p + 1);
        }

        // tile A P-bounce + PV; tile B's exp/pack already in regs above
        *(bf16x4*)(Pw + qr * PLD + quad * 4)      = waA;
        *(bf16x4*)(Pw + qr * PLD + 16 + quad * 4) = wbA;
        const bf16x8 pfA = *(const bf16x8*)(Pw + qr * PLD + quad * 8);
        __builtin_amdgcn_s_setprio(1);
        o0 = MFMA(va0, pfA, o0); o1 = MFMA(va1, pfA, o1);
        o2 = MFMA(va2, pfA, o2); o3 = MFMA(va3, pfA, o3);
        __builtin_amdgcn_s_setprio(0);

        // tile B reuses the same P slot (per-wave DS ops are in-order)
        *(bf16x4*)(Pw + qr * PLD + quad * 4)      = waB;
        *(bf16x4*)(Pw + qr * PLD + 16 + quad * 4) = wbB;
        const bf16x8 pfB = *(const bf16x8*)(Pw + qr * PLD + quad * 8);
        __builtin_amdgcn_s_setprio(1);
        o0 = MFMA(vb0, pfB, o0); o1 = MFMA(vb1, pfB, o1);
        o2 = MFMA(vb2, pfB, o2); o3 = MFMA(vb3, pfB, o3);
        __builtin_amdgcn_s_setprio(0);

        __syncthreads();    // buf[cur] readers done; buf[cur^1] staged
    }
#undef STAGE_PAIR
#undef SOFT_FULL
#undef SOFT_MASK

    // row sum of l across the 4 quads holding this row's k-partials
    l += __shfl_xor(l, 16); l += __shfl_xor(l, 32);
    const float n = 1.f / l;

    // o_vi C-layout: row(dh within tile) = quad*4+reg, col(q row) = qr
    const int s_ = qrow0 + qr;
    bf16* cp = ctx + ((size_t)s_ * BATCH_N + b) * DM + h * HDIM + quad * 4;
    #define CW(ov, vi_) do { \
        bf16x4 cc = {(bf16)(ov[0] * n), (bf16)(ov[1] * n), \
                     (bf16)(ov[2] * n), (bf16)(ov[3] * n)}; \
        *(bf16x4*)(cp + (vi_) * 16) = cc; \
    } while (0)
    CW(o0, 0); CW(o1, 1); CW(o2, 2); CW(o3, 3);
    #undef CW
}

// ---------------------------------------------------------------------------
// Output projection: ctx(4096x1024 bf16) @ out_w^T + out_b -> d_out f32 [s][b][d]
// 64x64 tile, grid (64 rows, 16 cols) = 1024 blocks = 4 blocks/CU (16 waves).
// WHY: r14's 2 blocks/CU retile gained -5.5 µs; proj remains latency-bound
// (2-phase barrier drain), so double residency again. LDS 16 KB; per-block
// step traffic 24 KB x 4 blocks = 96 KB/slot — under the ~144 KB/slot LDS
// wall qkv saturates, so the lower per-wave intensity (32x32 = 16 FLOP/elem)
// shouldn't bind. Rows-fastest grid keeps Wo-panel L2 locality.
// ---------------------------------------------------------------------------
__global__ __launch_bounds__(256)
void proj_kernel(const bf16* __restrict__ X, const bf16* __restrict__ W,
                 const float* __restrict__ bias, float* __restrict__ out) {
    __shared__ bf16 As[2][64 * 32];     // 8 KB
    __shared__ bf16 Bs[2][64 * 32];     // 8 KB
    const int row0 = blockIdx.x * 64;       // fastest dim = rows
    const int col0 = blockIdx.y * 64;
    const int tid  = threadIdx.x;
    const int lane = tid & 63;
    const int wv   = tid >> 6;
    const int wr = wv >> 1, wc = wv & 1;
    const int qr = lane & 15, quad = lane >> 4;

    // staging: 4 KB chunk (64 rows x 32 cols bf16); thread covers 16 B:
    // row = tid>>2, col = (tid&3)*8; LDS elem tid*8 = row*32+col (row-major).
    const int sr = tid >> 2;
    const int sc = (tid & 3) * 8;
    const bf16* Ap = X + (size_t)(row0 + sr) * DM + sc;
    const bf16* Wp = W + (size_t)(col0 + sr) * DM + sc;

    const f32x4 fzero = {0.f, 0.f, 0.f, 0.f};
    f32x4 acc[2][2];
    #pragma unroll
    for (int mi = 0; mi < 2; ++mi)
        #pragma unroll
        for (int ni = 0; ni < 2; ++ni)
            acc[mi][ni] = fzero;

#define PSTAGE(k0_, bi_) do { \
    async_cp16(Ap + (k0_), As[bi_] + tid * 8); \
    async_cp16(Wp + (k0_), Bs[bi_] + tid * 8); \
} while (0)

    PSTAGE(0, 0);
    __syncthreads();

    int cur = 0;
    for (int s = 0; s < 32; ++s) {          // K = 1024, BK = 32
        if (s + 1 < 32) PSTAGE((s + 1) << 5, cur ^ 1);

        bf16x8 af[2], bfr[2];
        #pragma unroll
        for (int mi = 0; mi < 2; ++mi)
            af[mi] = *(const bf16x8*)(As[cur] + (wr * 32 + mi * 16 + qr) * 32 + quad * 8);
        #pragma unroll
        for (int ni = 0; ni < 2; ++ni)
            bfr[ni] = *(const bf16x8*)(Bs[cur] + (wc * 32 + ni * 16 + qr) * 32 + quad * 8);
        #pragma unroll
        for (int mi = 0; mi < 2; ++mi)
            #pragma unroll
            for (int ni = 0; ni < 2; ++ni)
                acc[mi][ni] = __builtin_amdgcn_mfma_f32_16x16x32_bf16(
                    af[mi], bfr[ni], acc[mi][ni], 0, 0, 0);

        __syncthreads();
        cur ^= 1;
    }
#undef PSTAGE

    #pragma unroll
    for (int ni = 0; ni < 2; ++ni) {
        const int n = col0 + wc * 32 + ni * 16 + qr;
        const float bn = bias[n];
        #pragma unroll
        for (int mi = 0; mi < 2; ++mi) {
            #pragma unroll
            for (int r = 0; r < 4; ++r) {
                const int i = row0 + wr * 32 + mi * 16 + quad * 4 + r;
                out[(size_t)i * DM + n] = acc[mi][ni][r] + bn;
            }
        }
    }
}

extern "C" void kernel_launch(void* const* d_in, const int* in_sizes, int n_in,
                              void* d_out, int out_size, void* d_ws, size_t ws_size,
                              hipStream_t stream) {
    (void)in_sizes; (void)n_in; (void)out_size; (void)ws_size;
    const float* query = (const float*)d_in[0];
    const float* q_w   = (const float*)d_in[1];
    const float* q_b   = (const float*)d_in[2];
    const float* k_w   = (const float*)d_in[3];
    const float* k_b   = (const float*)d_in[4];
    const float* v_w   = (const float*)d_in[5];
    const float* v_b   = (const float*)d_in[6];
    const float* out_w = (const float*)d_in[7];
    const float* out_b = (const float*)d_in[8];
    // d_in[9] = attn_mask: deterministic causal -> recomputed in-kernel.

    // Workspace layout (peak 48 MB). Xb/Wqkv are dead after qkv_kernel.
    char* ws = (char*)d_ws;
    bf16*  Qb   = (bf16*)(ws);                        //  0..8   [b][h][s][dh]
    bf16*  Kb   = (bf16*)(ws + ((size_t)8  << 20));   //  8..16  [b][h][s][dh]
    bf16*  Vt   = (bf16*)(ws + ((size_t)16 << 20));   // 16..24  [b][h][dh][s]
    bf16*  ctx  = (bf16*)(ws + ((size_t)24 << 20));   // 24..32  [s*B+b][1024]
    bf16*  Wob  = (bf16*)(ws + ((size_t)32 << 20));   // 32..34
    bf16*  Xb   = (bf16*)(ws + ((size_t)34 << 20));   // 34..42 (dead after qkv)
    bf16*  Wqb  = (bf16*)(ws + ((size_t)42 << 20));   // 42..44 (dead after qkv)
    bf16*  Wkb  = (bf16*)(ws + ((size_t)44 << 20));   // 44..46 (dead after qkv)
    bf16*  Wvb  = (bf16*)(ws + ((size_t)46 << 20));   // 46..48 (dead after qkv)
    float* out  = (float*)d_out;

    dim3 blk(256);
    cvt_all<<<dim3(2048 + 4 * 512), blk, 0, stream>>>(
        query, q_w, k_w, v_w, out_w, Xb, Wqb, Wkb, Wvb, Wob);

    qkv_kernel<<<dim3((S_LEN * BATCH_N) / 128, DM / 128, 3), blk, 0, stream>>>(
        Xb, Wqb, q_b, Wkb, k_b, Wvb, v_b, Qb, Kb, Vt);
    attn_part<<<dim3(1024), blk, 0, stream>>>(Qb, Kb, Vt, ctx);
    proj_kernel<<<dim3((S_LEN * BATCH_N) / 64, DM / 64), blk, 0, stream>>>(
        ctx, Wob, out_b, out);
}